// Round 13
// baseline (449.285 us; speedup 1.0000x reference)
//
#include <hip/hip_runtime.h>
#include <hip/hip_bf16.h>

typedef __hip_bfloat16 bf16;
typedef __attribute__((ext_vector_type(8))) short short8;   // 8 bf16 = 4 VGPRs
typedef __attribute__((ext_vector_type(4))) short short4v;  // 4 bf16 = 2 VGPRs
typedef __attribute__((ext_vector_type(4))) float f32x4;    // MFMA acc

__device__ __forceinline__ float b2f(bf16 x){ return __bfloat162float(x); }
__device__ __forceinline__ bf16  f2b(float x){ return __float2bfloat16(x); }
__device__ __forceinline__ float s2f(short s){ bf16 t = *(bf16*)&s; return b2f(t); }

#define LOG2E 1.4426950408889634f

// raw v_exp_f32 (computes 2^x)
__device__ __forceinline__ float fexp2(float x){ return __builtin_amdgcn_exp2f(x); }

// fast silu: x * rcp(1+e^-x)  (v_rcp_f32, ~1ulp -- fine at bf16 output precision)
__device__ __forceinline__ float fsilu(float x){
  return x * __builtin_amdgcn_rcpf(1.f + fexp2(-LOG2E*x));
}

// dual-dtype input load / output store (flag: 1 = fp32 storage, 0 = bf16)
__device__ __forceinline__ float ldin(const void* p, size_t i, int f32){
  return f32 ? ((const float*)p)[i] : b2f(((const bf16*)p)[i]);
}
__device__ __forceinline__ void stout(void* p, size_t i, float v, int f32){
  if(f32) ((float*)p)[i] = v; else ((bf16*)p)[i] = f2b(v);
}

constexpr int SP   = 32*32*32;   // 32768 spatial per (b,c)
constexpr int LTOK = SP;         // tokens per batch
constexpr int NC   = 1024;       // scan chunks
constexpr int CLEN = LTOK / NC;  // 32
constexpr int NSEQ = 2*2*64*8;   // 2048 scan sequences (dir,b,d,n)
constexpr int SEG  = 32;         // scan2 hierarchy: 32 segments x 32 chunks
constexpr int SEGLEN = NC/SEG;   // 32

// ---------------------------------------------------------------- dtype detector
__global__ void k_detect(const void* conv_w, int* flag){
  if(threadIdx.x==0 && blockIdx.x==0){
    const bf16* p = (const bf16*)conv_w;
    int f = 0;
    for(int i=0;i<128;i++){
      float v = b2f(p[i]);
      if(!(v==v) || fabsf(v) > 1.0f) f = 1;   // bf16 weights are 0.05-scale
    }
    *flag = f;
  }
}

// ---------------------------------------------------------------- diagnostic fill
__global__ void k_fill(void* out, int n, const int* flag){
  const int f32 = *flag;
  int i = blockIdx.x*256 + threadIdx.x;
  if(i<n) stout(out, i, 12345.0f, f32);
}

// ---------------------------------------------------------------- weight re-layout: wt[tap][oc][ci] (+ zero the halo source buffer)
__global__ void k_wprep(const void* __restrict__ cw, bf16* __restrict__ wt,
                        float* __restrict__ zbuf, const int* __restrict__ flag){
  const int f32 = *flag;
  if(blockIdx.x==0 && threadIdx.x<32) zbuf[threadIdx.x] = 0.f;   // 128B zeros for convm halo
  int t = blockIdx.x*256 + threadIdx.x;   // 110592 = 27*64*64
  if(t >= 27*64*64) return;
  int tap = t >> 12;          // /4096
  int oc  = (t >> 6) & 63;
  int ci  = t & 63;
  wt[t] = f2b(ldin(cw, ((size_t)(oc*64+ci))*27 + tap, f32));
}

// ---------------------------------------------------------------- in_proj as MFMA GEMM
__global__ __launch_bounds__(256) void k_inprojm(
    const void* __restrict__ in, const void* __restrict__ pw,
    bf16* __restrict__ xz, bf16* __restrict__ xin_t,
    const int* __restrict__ flag){
  const int f32 = *flag;
  __shared__ bf16 tok[128*72];   // [token][c], pitch 72
  __shared__ bf16 wl [128*72];   // [j][c],     pitch 72
  int tid = threadIdx.x;
  int b = blockIdx.x >> 8, tile = blockIdx.x & 255;
  int l0 = tile*128;

  for(int p=tid; p<1024; p+=256){          // weights: (j, c8)
    int j = p & 127, c8 = p >> 7;
    short8 v;
    #pragma unroll
    for(int k=0;k<8;k++){
      bf16 t = f2b(ldin(pw, j*64 + c8*8 + k, f32));
      v[k] = *(short*)&t;
    }
    *(short8*)(&wl[j*72 + c8*8]) = v;
  }
  for(int p=tid; p<1024; p+=256){          // tokens: (i, c8), coalesced over i
    int i = p & 127, c8 = p >> 7;
    short8 v;
    #pragma unroll
    for(int k=0;k<8;k++){
      bf16 t = f2b(ldin(in, ((size_t)(b*64 + c8*8 + k))*SP + l0 + i, f32));
      v[k] = *(short*)&t;
    }
    *(short8*)(&tok[i*72 + c8*8]) = v;
  }
  __syncthreads();

  int lane = tid & 63, wv = tid >> 6;
  int pn = lane & 15, quad = lane >> 4, kg8 = quad*8;
  f32x4 acc[2][8];
  #pragma unroll
  for(int mt=0;mt<2;mt++)
    #pragma unroll
    for(int nt=0;nt<8;nt++) acc[mt][nt]=(f32x4)(0.f);

  #pragma unroll
  for(int kq=0;kq<2;kq++){
    short8 a0 = *(const short8*)(&tok[(wv*32      + pn)*72 + kq*32 + kg8]);
    short8 a1 = *(const short8*)(&tok[(wv*32 + 16 + pn)*72 + kq*32 + kg8]);
    #pragma unroll
    for(int nt=0;nt<8;nt++){
      short8 bb = *(const short8*)(&wl[(nt*16+pn)*72 + kq*32 + kg8]);
      acc[0][nt] = __builtin_amdgcn_mfma_f32_16x16x32_bf16(a0,bb,acc[0][nt],0,0,0);
      acc[1][nt] = __builtin_amdgcn_mfma_f32_16x16x32_bf16(a1,bb,acc[1][nt],0,0,0);
    }
  }

  #pragma unroll
  for(int mt=0;mt<2;mt++){
    #pragma unroll
    for(int nt=0;nt<8;nt++){
      #pragma unroll
      for(int r=0;r<4;r++){
        int token = wv*32 + mt*16 + quad*4 + r;
        xz[((size_t)b*LTOK + l0 + token)*128 + nt*16 + pn] = f2b(acc[mt][nt][r]);
      }
    }
  }
  for(int p=tid; p<8192; p+=256){
    int i = p >> 6, c = p & 63;
    xin_t[((size_t)b*SP + l0 + i)*64 + c] = tok[i*72 + c];
  }
}

// ---------------------------------------------------------------- MFMA conv3d (both convs)
// R21: w-split-8 tile 3h x 10w x 18d x 32ci = 540 rows x 64B = 36.9KB LDS
// -> 4 blocks/CU (2x TLP vs R20's 2). Keeps BOTH proven granularities:
//   - writes: 32B contiguous per (oc,h,w) (d-half, pn = d-pos) = R18/R20 exact
//   - reads: pn -> consecutive rix, same XOR-quad swizzle (proven 0-conflict)
// R19 lesson (16B partial-line writes explode WRITE 4.6x) explicitly avoided.
__global__ __launch_bounds__(256, 4) void k_convm(
    const bf16* __restrict__ xin_t, const bf16* __restrict__ wt,
    const void* __restrict__ cb, const bf16* __restrict__ skip,
    bf16* __restrict__ out_bf, void* __restrict__ out_any,
    int mode, const int* __restrict__ flag, const float* __restrict__ zbuf){
  const int f32 = *flag;
  __shared__ bf16 xt[2304*8];  // 2304 16B-units = 36,864 B (540*4=2160 used + pad)

  int tid  = threadIdx.x;
  int lane = tid & 63;
  int wv   = tid >> 6;
  int pn   = lane & 15;
  int quad = lane >> 4;
  int kg8  = quad * 8;
  int laneA = pn*64 + kg8;

  int blk0 = blockIdx.x;                       // 2048 blocks
  int blk  = (blk0 & 7)*256 + (blk0 >> 3);     // bijective XCD-contiguous remap
  int ocg = blk & 3;
  int wq  = (blk >> 2) & 3;
  int dh2 = (blk >> 4) & 1;
  int h   = (blk >> 5) & 31;
  int b   = blk >> 10;
  int w0  = wq*8;
  int d0  = dh2*16;

  f32x4 acc[2];                 // [wr]
  acc[0]=(f32x4)(0.f); acc[1]=(f32x4)(0.f);

  for(int cic=0; cic<64; cic+=32){
    if(cic) __syncthreads();
    // stage 3h x 10w x 18d x 32ci via LDS-DMA; every unit (incl. pad) written
    {
      bf16* dstw = &xt[(size_t)(wv*64)*8];     // wave-uniform base, lane x 16B implicit
      for(int it=0; it<9; it++){
        int j = it*256 + tid;                  // physical 16B unit (linear)
        int row = j >> 2;
        int q4  = (j & 3) ^ ((j >> 3) & 3);    // inverse swizzle -> logical ci-quad
        int hh = row / 180; int rem = row - hh*180;
        int ww = rem / 18;  int dd = rem - ww*18;
        int hg = h + hh - 1, wg = w0 + ww - 1, d = d0 + dd - 1;
        bool ok = (j < 2160) && ((unsigned)hg < 32u) && ((unsigned)wg < 32u) && ((unsigned)d < 32u);
        const void* src = ok
          ? (const void*)&xin_t[(((size_t)b*SP) + hg*1024 + wg*32 + d)*64 + cic + q4*8]
          : (const void*)zbuf;
        __builtin_amdgcn_global_load_lds(
            (const __attribute__((address_space(1))) void*)src,
            (__attribute__((address_space(3))) void*)(dstw + (size_t)it*256*8),
            16, 0, 0);
      }
    }
    __syncthreads();

    // hoist all 27 taps' A-frags for this ocg+chunk into registers
    short8 afr[27];
    #pragma unroll
    for(int t=0;t<27;t++)
      afr[t] = *(const short8*)(wt + t*4096 + ocg*1024 + cic + laneA);

    #pragma unroll
    for(int kz=0;kz<3;kz++){
      #pragma unroll
      for(int ky=0;ky<3;ky++){
        #pragma unroll
        for(int kx=0;kx<3;kx++){
          int tap = (kz*3+ky)*3+kx;
          #pragma unroll
          for(int wr=0;wr<2;wr++){
            int rix = (kz*10 + wv*2 + wr + ky)*18 + kx + pn;
            int punit = rix*4 + (quad ^ ((rix>>1)&3));   // swizzled read
            short8 bb = *(const short8*)(&xt[(size_t)punit*8]);
            acc[wr] = __builtin_amdgcn_mfma_f32_16x16x32_bf16(afr[tap], bb, acc[wr], 0,0,0);
          }
        }
      }
    }
  }

  #pragma unroll
  for(int wr=0;wr<2;wr++){
    #pragma unroll
    for(int r=0;r<4;r++){
      int oc = ocg*16 + quad*4 + r;
      size_t idx = ((size_t)(b*64+oc))*SP + h*1024 + (w0 + wv*2 + wr)*32 + d0 + pn;
      float v = acc[wr][r] + ldin(cb, oc, f32);
      if(mode==0) out_bf[idx] = f2b(v);
      else        stout(out_any, idx, v + b2f(skip[idx]), f32);
    }
  }
}

// ---------------------------------------------------------------- instance norm + relu (in place, bf16)
__global__ void k_inorm(bf16* __restrict__ buf){
  int bc = blockIdx.x;
  bf16* p = buf + (size_t)bc*SP;
  float s=0.f, s2=0.f;
  for(int i=threadIdx.x;i<SP;i+=256){ float v=b2f(p[i]); s+=v; s2+=v*v; }
  __shared__ float sh[8];
  #pragma unroll
  for(int m=32;m>=1;m>>=1){ s += __shfl_xor(s,m); s2 += __shfl_xor(s2,m); }
  int wid = threadIdx.x>>6;
  if((threadIdx.x&63)==0){ sh[wid]=s; sh[4+wid]=s2; }
  __syncthreads();
  if(threadIdx.x==0){ float a=0,b2=0; for(int i=0;i<4;i++){a+=sh[i]; b2+=sh[4+i];} sh[0]=a; sh[4]=b2; }
  __syncthreads();
  float mean = sh[0]*(1.f/SP);
  float var  = sh[4]*(1.f/SP) - mean*mean;
  float inv = rsqrtf(fmaxf(var,0.f) + 1e-5f);
  for(int i=threadIdx.x;i<SP;i+=256){
    float v=(b2f(p[i])-mean)*inv;
    p[i] = f2b(v>0.f ? v : 0.f);
  }
}

// ---------------------------------------------------------------- per-direction prep: conv1d+silu, x_proj
// R14 structure; R18: rcp-silu.
__global__ __launch_bounds__(256) void k_dirprep(
                          const bf16* __restrict__ xz, const void* __restrict__ c1w,
                          const void* __restrict__ c1b, const void* __restrict__ xpw,
                          bf16* __restrict__ bcg, float* __restrict__ dtr,
                          const int* __restrict__ flag){
  const int f32 = *flag;
  __shared__ float xs[67][64];
  __shared__ float xcs[64][68];   // pitch 68 floats: 16B-aligned rows
  __shared__ float xws[20][68];
  int bid = blockIdx.x;
  int g = bid >> 10, b = (bid>>9)&1, tile = bid & 511;
  int l0 = tile*64;
  int gb = g*2+b;
  int tid = threadIdx.x;
  for(int t=tid; t<20*64; t+=256){ int j=t>>6, d=t&63; xws[j][d]=ldin(xpw, t, f32); }
  for(int t=tid; t<67*64; t+=256){
    int row=t>>6, d=t&63;
    int l = l0 + row - 3;
    float v = 0.f;
    if(l>=0 && l<LTOK){
      int lg = g ? (LTOK-1-l) : l;
      v = b2f(xz[((size_t)b*LTOK + lg)*128 + d]);
    }
    xs[row][d]=v;
  }
  __syncthreads();
  {
    int d = tid & 63;
    float cw0=ldin(c1w,d*4+0,f32), cw1=ldin(c1w,d*4+1,f32),
          cw2=ldin(c1w,d*4+2,f32), cw3=ldin(c1w,d*4+3,f32);
    float cb_=ldin(c1b,d,f32);
    for(int tl = tid>>6; tl<64; tl+=4){
      float acc = cb_ + cw0*xs[tl][d] + cw1*xs[tl+1][d] + cw2*xs[tl+2][d] + cw3*xs[tl+3][d];
      xcs[tl][d] = fsilu(acc);
    }
  }
  __syncthreads();
  {
    int tl = tid & 63, wq = tid >> 6;      // wave wq owns j = wq*5 .. wq*5+4
    float acc[5] = {0.f,0.f,0.f,0.f,0.f};
    #pragma unroll 4
    for(int d4=0; d4<16; d4++){
      float4 xv = *(const float4*)(&xcs[tl][d4*4]);
      #pragma unroll
      for(int jj=0; jj<5; jj++){
        float4 wv = *(const float4*)(&xws[wq*5+jj][d4*4]);   // wave-broadcast
        acc[jj] += xv.x*wv.x + xv.y*wv.y + xv.z*wv.z + xv.w*wv.w;
      }
    }
    size_t l = (size_t)gb*LTOK + l0 + tl;
    #pragma unroll
    for(int jj=0; jj<5; jj++){
      int j = wq*5 + jj;
      if(j<4) dtr[l*4 + j] = acc[jj];
      else    bcg[l*16 + (j-4)] = f2b(acc[jj]);
    }
  }
}

// ---------------------------------------------------------------- scan pass1: 2-wave n-split, exp-chain fast path (R18)
__global__ __launch_bounds__(128, 4) void k_scan1(
                        const bf16* __restrict__ xz, const float* __restrict__ dtr,
                        const bf16* __restrict__ bcg,
                        const void* __restrict__ c1w, const void* __restrict__ c1b,
                        const void* __restrict__ dpw, const void* __restrict__ dpb,
                        const void* __restrict__ alog, const void* __restrict__ ablog,
                        float* __restrict__ psP, float* __restrict__ psS,
                        const int* __restrict__ flag){
  const int f32 = *flag;
  int bid = blockIdx.x;              // 4096 = 2g * 2b * NC
  int lane = threadIdx.x & 63;
  int nh   = threadIdx.x >> 6;       // n-half (0 or 1)
  int chunk = bid & (NC-1);
  int b = (bid>>10)&1;
  int g = bid>>11;
  int gb = g*2+b;
  const void* al = g ? ablog : alog;
  float ac2[4];                      // exp2-ready: ac * log2(e)
  #pragma unroll
  for(int n=0;n<4;n++) ac2[n] = -LOG2E*__expf(ldin(al, lane*8 + nh*4 + n, f32));
  // A-structure detection: ac[n] ~ acb * (nh*4+n+1)  (exact for this model's A_log)
  float m0 = (float)(nh*4+1);
  float acb2 = ac2[0] / m0;
  bool okl = true;
  #pragma unroll
  for(int n=1;n<4;n++) okl = okl && (fabsf(ac2[n] - acb2*(m0+n)) <= 0.01f*fabsf(ac2[n]));
  const bool fastA = __all(okl);
  float cw0=ldin(c1w,lane*4+0,f32), cw1=ldin(c1w,lane*4+1,f32), cw2=ldin(c1w,lane*4+2,f32), cw3=ldin(c1w,lane*4+3,f32);
  float cb_=ldin(c1b,lane,f32);
  float dw0=ldin(dpw,lane*4+0,f32), dw1=ldin(dpw,lane*4+1,f32), dw2=ldin(dpw,lane*4+2,f32), dw3=ldin(dpw,lane*4+3,f32);
  float db_=ldin(dpb,lane,f32);
  float S[4];
  #pragma unroll
  for(int n=0;n<4;n++) S[n]=0.f;
  float Tsum = 0.f;
  int lt0 = chunk*CLEN;
  float x0,x1,x2;
  {
    float xr[3];
    #pragma unroll
    for(int j=0;j<3;j++){
      int lt = lt0-3+j;
      float v=0.f;
      if(lt>=0){ int lg = g ? (LTOK-1-lt) : lt; v=b2f(xz[((size_t)b*LTOK+lg)*128 + lane]); }
      xr[j]=v;
    }
    x0=xr[0]; x1=xr[1]; x2=xr[2];
  }
  for(int i0=0;i0<CLEN;i0+=8){
    bf16 xv[8]; float4 dv[8]; short4v bb[8];
    #pragma unroll
    for(int k=0;k<8;k++){
      int lt = lt0+i0+k;
      int lg = g ? (LTOK-1-lt) : lt;
      xv[k] = xz[((size_t)b*LTOK+lg)*128 + lane];
      size_t l = (size_t)gb*LTOK + lt;
      dv[k] = *(const float4*)(dtr + l*4);
      bb[k] = *(const short4v*)(bcg + l*16 + nh*4);
    }
    #pragma unroll
    for(int k=0;k<8;k++){
      float x3 = b2f(xv[k]);
      float pre = cb_ + cw0*x0 + cw1*x1 + cw2*x2 + cw3*x3;
      float xc = fsilu(pre);
      float v = db_ + dv[k].x*dw0 + dv[k].y*dw1 + dv[k].z*dw2 + dv[k].w*dw3;
      float e = fexp2(-LOG2E*fabsf(v));
      float dt = fmaxf(v,0.f) + __logf(1.f+e);
      Tsum += dt;
      float bx = dt*xc;
      float a[4];
      if(fastA){
        float e1 = fexp2(dt*acb2);
        if(nh==0){ a[0]=e1; a[1]=e1*e1; a[2]=a[1]*e1; a[3]=a[1]*a[1]; }
        else { float e2=e1*e1, e4=e2*e2; a[0]=e4*e1; a[1]=e4*e2; a[2]=a[1]*e1; a[3]=e4*e4; }
      }else{
        #pragma unroll
        for(int n=0;n<4;n++) a[n] = fexp2(dt*ac2[n]);
      }
      #pragma unroll
      for(int n=0;n<4;n++) S[n] = a[n]*S[n] + bx*s2f(bb[k][n]);
      x0=x1; x1=x2; x2=x3;
    }
  }
  int seq = (gb*64 + lane)*8 + nh*4;
  #pragma unroll
  for(int n=0;n<4;n++){
    psP[(size_t)chunk*NSEQ + seq + n] = fexp2(ac2[n]*Tsum);
    psS[(size_t)chunk*NSEQ + seq + n] = S[n];
  }
}

// ---------------------------------------------------------------- scan pass2: hierarchical (depth 1024 -> 32/32/32)
__global__ void k_scan2a(const float* __restrict__ psP, const float* __restrict__ psS,
                         float* __restrict__ segP, float* __restrict__ segS){
  int idx = blockIdx.x*256 + threadIdx.x;       // 65536 = NSEQ*SEG
  int seq = idx & (NSEQ-1);
  int seg = idx >> 11;
  float P = 1.f, S = 0.f;
  int i0 = seg*SEGLEN;
  #pragma unroll 4
  for(int i=0;i<SEGLEN;i++){
    float p = psP[(size_t)(i0+i)*NSEQ + seq];
    float s = psS[(size_t)(i0+i)*NSEQ + seq];
    S = p*S + s;
    P *= p;
  }
  segP[seg*NSEQ + seq] = P;
  segS[seg*NSEQ + seq] = S;
}
__global__ void k_scan2b(const float* __restrict__ segP, const float* __restrict__ segS,
                         float* __restrict__ segC){
  int seq = blockIdx.x*256 + threadIdx.x;
  if(seq >= NSEQ) return;
  float h = 0.f;
  #pragma unroll
  for(int s=0;s<SEG;s++){
    segC[s*NSEQ + seq] = h;
    h = segP[s*NSEQ + seq]*h + segS[s*NSEQ + seq];
  }
}
__global__ void k_scan2c(const float* __restrict__ psP, const float* __restrict__ segC,
                         float* __restrict__ psC){
  int idx = blockIdx.x*256 + threadIdx.x;
  int seq = idx & (NSEQ-1);
  int seg = idx >> 11;
  float h = segC[seg*NSEQ + seq];
  int i0 = seg*SEGLEN;
  #pragma unroll 4
  for(int i=0;i<SEGLEN;i++){
    float p = psP[(size_t)(i0+i)*NSEQ + seq];
    float s = psC[(size_t)(i0+i)*NSEQ + seq];   // read partial BEFORE overwrite
    psC[(size_t)(i0+i)*NSEQ + seq] = h;
    h = p*h + s;
  }
}

// ---------------------------------------------------------------- scan pass3: 2-wave n-split, LDS y-combine, exp-chain fast path (R18)
__global__ __launch_bounds__(128, 4) void k_scan3(
                        const bf16* __restrict__ xz, const float* __restrict__ dtr,
                        const bf16* __restrict__ bcg,
                        const void* __restrict__ c1w, const void* __restrict__ c1b,
                        const void* __restrict__ dpw, const void* __restrict__ dpb,
                        const void* __restrict__ alog, const void* __restrict__ ablog,
                        const void* __restrict__ dskip, const float* __restrict__ carry,
                        bf16* __restrict__ ybuf, const int* __restrict__ flag){
  const int f32 = *flag;
  __shared__ float ysh[2][8][64];    // 4 KB double buffer
  int bid = blockIdx.x;              // 4096
  int lane = threadIdx.x & 63;
  int nh   = threadIdx.x >> 6;
  int chunk = bid & (NC-1);
  int b = (bid>>10)&1;
  int g = bid>>11;
  int gb = g*2+b;
  const void* al = g ? ablog : alog;
  float ac2[4];
  #pragma unroll
  for(int n=0;n<4;n++) ac2[n] = -LOG2E*__expf(ldin(al, lane*8 + nh*4 + n, f32));
  float m0 = (float)(nh*4+1);
  float acb2 = ac2[0] / m0;
  bool okl = true;
  #pragma unroll
  for(int n=1;n<4;n++) okl = okl && (fabsf(ac2[n] - acb2*(m0+n)) <= 0.01f*fabsf(ac2[n]));
  const bool fastA = __all(okl);
  float cw0=ldin(c1w,lane*4+0,f32), cw1=ldin(c1w,lane*4+1,f32), cw2=ldin(c1w,lane*4+2,f32), cw3=ldin(c1w,lane*4+3,f32);
  float cb_=ldin(c1b,lane,f32);
  float dw0=ldin(dpw,lane*4+0,f32), dw1=ldin(dpw,lane*4+1,f32), dw2=ldin(dpw,lane*4+2,f32), dw3=ldin(dpw,lane*4+3,f32);
  float db_=ldin(dpb,lane,f32);
  float dsk = ldin(dskip,lane,f32);
  int seq = (gb*64 + lane)*8 + nh*4;
  float h[4];
  #pragma unroll
  for(int n=0;n<4;n++) h[n] = carry[(size_t)chunk*NSEQ + seq + n];
  int lt0 = chunk*CLEN;
  float x0,x1,x2;
  {
    float xr[3];
    #pragma unroll
    for(int j=0;j<3;j++){
      int lt = lt0-3+j;
      float v=0.f;
      if(lt>=0){ int lg = g ? (LTOK-1-lt) : lt; v=b2f(xz[((size_t)b*LTOK+lg)*128 + lane]); }
      xr[j]=v;
    }
    x0=xr[0]; x1=xr[1]; x2=xr[2];
  }
  for(int i0=0;i0<CLEN;i0+=8){
    int bt = (i0>>3)&1;
    bf16 xv[8]; float4 dv[8]; short4v bb[8], cc[8];
    #pragma unroll
    for(int k=0;k<8;k++){
      int lt = lt0+i0+k;
      int lg = g ? (LTOK-1-lt) : lt;
      xv[k] = xz[((size_t)b*LTOK+lg)*128 + lane];
      size_t l = (size_t)gb*LTOK + lt;
      dv[k] = *(const float4*)(dtr + l*4);
      bb[k] = *(const short4v*)(bcg + l*16 + nh*4);
      cc[k] = *(const short4v*)(bcg + l*16 + 8 + nh*4);
    }
    float py[8];
    #pragma unroll
    for(int k=0;k<8;k++){
      float x3 = b2f(xv[k]);
      float pre = cb_ + cw0*x0 + cw1*x1 + cw2*x2 + cw3*x3;
      float xc = fsilu(pre);
      float v = db_ + dv[k].x*dw0 + dv[k].y*dw1 + dv[k].z*dw2 + dv[k].w*dw3;
      float e = fexp2(-LOG2E*fabsf(v));
      float dt = fmaxf(v,0.f) + __logf(1.f+e);
      float bx = dt*xc;
      float part = nh ? xc*dsk : 0.f;
      float a[4];
      if(fastA){
        float e1 = fexp2(dt*acb2);
        if(nh==0){ a[0]=e1; a[1]=e1*e1; a[2]=a[1]*e1; a[3]=a[1]*a[1]; }
        else { float e2=e1*e1, e4=e2*e2; a[0]=e4*e1; a[1]=e4*e2; a[2]=a[1]*e1; a[3]=e4*e4; }
      }else{
        #pragma unroll
        for(int n=0;n<4;n++) a[n] = fexp2(dt*ac2[n]);
      }
      #pragma unroll
      for(int n=0;n<4;n++){
        h[n] = a[n]*h[n] + bx*s2f(bb[k][n]);
        part += h[n]*s2f(cc[k][n]);
      }
      if(nh==0) ysh[bt][k][lane] = part;
      else      py[k] = part;
      x0=x1; x1=x2; x2=x3;
    }
    __syncthreads();
    if(nh==1){
      #pragma unroll
      for(int k=0;k<8;k++){
        size_t l = (size_t)gb*LTOK + lt0+i0+k;
        ybuf[l*64 + lane] = f2b(ysh[bt][k][lane] + py[k]);
      }
    }
  }
}

// ---------------------------------------------------------------- combine dirs * silu(z) + out_proj (MFMA) + LN -> vol (token-major)
__global__ __launch_bounds__(256) void k_outln(
                        const bf16* __restrict__ ybuf, const bf16* __restrict__ xz,
                        const void* __restrict__ opw,
                        const void* __restrict__ lng, const void* __restrict__ lnb,
                        bf16* __restrict__ vol_t, const int* __restrict__ flag){
  const int f32 = *flag;
  __shared__ bf16 vsm[64*72];   // [token][d] pitch 72; reused for LN output staging
  __shared__ bf16 wsm[64*72];   // [c][d]     pitch 72
  __shared__ float gsm[64], bsm[64];
  int tid = threadIdx.x;
  int b = blockIdx.x >> 9, tile = blockIdx.x & 511;
  int l0 = tile*64;

  for(int p=tid; p<512; p+=256){           // weights (c, d8)
    int c = p & 63, d8 = p >> 6;
    short8 v;
    #pragma unroll
    for(int k=0;k<8;k++){ bf16 t = f2b(ldin(opw, c*64 + d8*8 + k, f32)); v[k] = *(short*)&t; }
    *(short8*)(&wsm[c*72 + d8*8]) = v;
  }
  if(tid<64){ gsm[tid]=ldin(lng,tid,f32); bsm[tid]=ldin(lnb,tid,f32); }
  for(int p=tid; p<4096; p+=256){          // v = 0.5(yf+yb)*silu(z)
    int tl = p >> 6, d = p & 63;
    int l = l0 + tl;
    float yf = b2f(ybuf[((size_t)(0+b)*LTOK + l)*64 + d]);
    float yb = b2f(ybuf[((size_t)(2+b)*LTOK + (LTOK-1-l))*64 + d]);
    float z  = b2f(xz[((size_t)b*LTOK + l)*128 + 64 + d]);
    vsm[tl*72 + d] = f2b(0.5f*(yf+yb)*fsilu(z));
  }
  __syncthreads();

  int lane = tid & 63, wv = tid >> 6, pn = lane & 15, quad = lane >> 4, kg8 = quad*8;
  f32x4 acc[4];
  #pragma unroll
  for(int nt=0;nt<4;nt++) acc[nt]=(f32x4)(0.f);
  #pragma unroll
  for(int kq=0;kq<2;kq++){
    short8 a = *(const short8*)(&vsm[(wv*16+pn)*72 + kq*32 + kg8]);
    #pragma unroll
    for(int nt=0;nt<4;nt++){
      short8 bb = *(const short8*)(&wsm[(nt*16+pn)*72 + kq*32 + kg8]);
      acc[nt] = __builtin_amdgcn_mfma_f32_16x16x32_bf16(a,bb,acc[nt],0,0,0);
    }
  }
  __syncthreads();   // all reads of vsm done; safe to overwrite below

  float gl[4], bl[4];
  #pragma unroll
  for(int nt=0;nt<4;nt++){ gl[nt]=gsm[nt*16+pn]; bl[nt]=bsm[nt*16+pn]; }
  #pragma unroll
  for(int r=0;r<4;r++){
    float vals[4]; float s=0.f;
    #pragma unroll
    for(int nt=0;nt<4;nt++){ vals[nt]=acc[nt][r]; s+=vals[nt]; }
    #pragma unroll
    for(int m=1;m<16;m<<=1) s += __shfl_xor(s, m);
    float mu = s*(1.f/64.f);
    float s2=0.f;
    #pragma unroll
    for(int nt=0;nt<4;nt++){ float dv=vals[nt]-mu; s2+=dv*dv; }
    #pragma unroll
    for(int m=1;m<16;m<<=1) s2 += __shfl_xor(s2, m);
    float inv = rsqrtf(s2*(1.f/64.f) + 1e-5f);
    int token = wv*16 + quad*4 + r;
    #pragma unroll
    for(int nt=0;nt<4;nt++){
      vsm[token*72 + nt*16 + pn] = f2b((vals[nt]-mu)*inv*gl[nt] + bl[nt]);
    }
  }
  __syncthreads();
  for(int p=tid; p<512; p+=256){           // coalesced token-major short8 stores
    int tl = p >> 3, d8 = p & 7;
    *(short8*)(&vol_t[((size_t)b*SP + l0 + tl)*64 + d8*8]) = *(const short8*)(&vsm[tl*72 + d8*8]);
  }
}

// ---------------------------------------------------------------- launch
extern "C" void kernel_launch(void* const* d_in, const int* in_sizes, int n_in,
                              void* d_out, int out_size, void* d_ws, size_t ws_size,
                              hipStream_t stream){
  const void* input  = d_in[0];
  const void* conv_w = d_in[1];
  const void* conv_b = d_in[2];
  const void* inpw   = d_in[3];
  const void* c1w    = d_in[4];
  const void* c1b    = d_in[5];
  const void* xpw    = d_in[6];
  const void* dpw    = d_in[7];
  const void* dpb    = d_in[8];
  const void* alog   = d_in[9];
  const void* ablog  = d_in[10];
  const void* dskip  = d_in[11];
  const void* opw    = d_in[12];
  const void* lng    = d_in[13];
  const void* lnb    = d_in[14];

  // R14 layout (NC=1024): psP/psS 8.4 MB; aliasing keeps NEED < 58 MB.
  //   ybuf (16.8M) aliases psP(8.4M)+xin_t(8.4M)  [both dead before scan3 writes ybuf]
  //   vol_t (8.4M) aliases psS                    [carry dead after scan3]
  char* base = (char*)d_ws;
  bf16*  skipb = (bf16*) (base + 0);            //  8,388,608 B
  bf16*  xz    = (bf16*) (base + 8388608);      // 16,777,216 B -> 25,165,824
  bf16*  bcg   = (bf16*) (base + 25165824);     //  4,194,304 B -> 29,360,128
  float* dtr   = (float*)(base + 29360128);     //  2,097,152 B -> 31,457,280
  float* psP   = (float*)(base + 31457280);     //  8,388,608 B -> 39,845,888 (NC*NSEQ*4)
  bf16*  xin_t = (bf16*) (base + 39845888);     //  8,388,608 B -> 48,234,496 (alias ybuf-hi)
  bf16*  ybuf  = (bf16*) (base + 31457280);     // 16,777,216 B alias psP+xin_t
  float* psS   = (float*)(base + 48234496);     //  8,388,608 B -> 56,623,104 (carry; vol_t alias)
  bf16*  vol_t = (bf16*) (base + 48234496);     //  8,388,608 B alias psS
  bf16*  wt    = (bf16*) (base + 56623104);     //    221,184 B -> 56,844,288
  float* segP  = (float*)(base + 56844288);     //    262,144 B -> 57,106,432
  float* segS  = (float*)(base + 57106432);     //    262,144 B -> 57,368,576
  float* segC  = (float*)(base + 57368576);     //    262,144 B -> 57,630,720
  int*   flagp = (int*)  (base + 57630720);     //  16 B -> 57,630,736
  float* zbuf  = (float*)(base + 57630736);     //  128 B zeros (convm halo source)
  const size_t NEED = 57630864;

  k_detect<<<dim3(1), dim3(64), 0, stream>>>(conv_w, flagp);

  if(ws_size < NEED){
    k_fill<<<dim3((out_size+255)/256), dim3(256), 0, stream>>>(d_out, out_size, flagp);
    return;
  }

  k_wprep  <<<dim3(432),   dim3(256), 0, stream>>>(conv_w, wt, zbuf, flagp);
  k_inprojm<<<dim3(512),   dim3(256), 0, stream>>>(input, inpw, xz, xin_t, flagp);
  // conv #1: xin_t -> skipb (bf16, channel-major out)
  k_convm  <<<dim3(2048),  dim3(256), 0, stream>>>(xin_t, wt, conv_b, nullptr, skipb, nullptr, 0, flagp, zbuf);
  k_inorm  <<<dim3(128),   dim3(256), 0, stream>>>(skipb);
  k_dirprep<<<dim3(2048),  dim3(256), 0, stream>>>(xz, c1w, c1b, xpw, bcg, dtr, flagp);
  k_scan1  <<<dim3(4096),  dim3(128), 0, stream>>>(xz, dtr, bcg, c1w, c1b, dpw, dpb, alog, ablog, psP, psS, flagp);
  k_scan2a <<<dim3(256),   dim3(256), 0, stream>>>(psP, psS, segP, segS);
  k_scan2b <<<dim3(8),     dim3(256), 0, stream>>>(segP, segS, segC);
  k_scan2c <<<dim3(256),   dim3(256), 0, stream>>>(psP, segC, psS);
  k_scan3  <<<dim3(4096),  dim3(128), 0, stream>>>(xz, dtr, bcg, c1w, c1b, dpw, dpb, alog, ablog, dskip, psS, ybuf, flagp);
  k_outln  <<<dim3(1024),  dim3(256), 0, stream>>>(ybuf, xz, opw, lng, lnb, vol_t, flagp);
  // conv #2: vol_t (+skipb) -> d_out, dual-dtype out
  k_convm  <<<dim3(2048),  dim3(256), 0, stream>>>(vol_t, wt, conv_b, skipb, nullptr, d_out, 1, flagp, zbuf);
}

// Round 14
// 434.690 us; speedup vs baseline: 1.0336x; 1.0336x over previous
//
#include <hip/hip_runtime.h>
#include <hip/hip_bf16.h>

typedef __hip_bfloat16 bf16;
typedef __attribute__((ext_vector_type(8))) short short8;   // 8 bf16 = 4 VGPRs
typedef __attribute__((ext_vector_type(4))) short short4v;  // 4 bf16 = 2 VGPRs
typedef __attribute__((ext_vector_type(4))) float f32x4;    // MFMA acc

__device__ __forceinline__ float b2f(bf16 x){ return __bfloat162float(x); }
__device__ __forceinline__ bf16  f2b(float x){ return __float2bfloat16(x); }
__device__ __forceinline__ float s2f(short s){ bf16 t = *(bf16*)&s; return b2f(t); }

#define LOG2E 1.4426950408889634f

// raw v_exp_f32 (computes 2^x)
__device__ __forceinline__ float fexp2(float x){ return __builtin_amdgcn_exp2f(x); }

// fast silu: x * rcp(1+e^-x)  (v_rcp_f32, ~1ulp -- fine at bf16 output precision)
__device__ __forceinline__ float fsilu(float x){
  return x * __builtin_amdgcn_rcpf(1.f + fexp2(-LOG2E*x));
}

// dual-dtype input load / output store (flag: 1 = fp32 storage, 0 = bf16)
__device__ __forceinline__ float ldin(const void* p, size_t i, int f32){
  return f32 ? ((const float*)p)[i] : b2f(((const bf16*)p)[i]);
}
__device__ __forceinline__ void stout(void* p, size_t i, float v, int f32){
  if(f32) ((float*)p)[i] = v; else ((bf16*)p)[i] = f2b(v);
}

constexpr int SP   = 32*32*32;   // 32768 spatial per (b,c)
constexpr int LTOK = SP;         // tokens per batch
constexpr int NC   = 1024;       // scan chunks
constexpr int CLEN = LTOK / NC;  // 32
constexpr int NSEQ = 2*2*64*8;   // 2048 scan sequences (dir,b,d,n)
constexpr int SEG  = 32;         // scan2 hierarchy: 32 segments x 32 chunks
constexpr int SEGLEN = NC/SEG;   // 32

// ---------------------------------------------------------------- dtype detector
__global__ void k_detect(const void* conv_w, int* flag){
  if(threadIdx.x==0 && blockIdx.x==0){
    const bf16* p = (const bf16*)conv_w;
    int f = 0;
    for(int i=0;i<128;i++){
      float v = b2f(p[i]);
      if(!(v==v) || fabsf(v) > 1.0f) f = 1;   // bf16 weights are 0.05-scale
    }
    *flag = f;
  }
}

// ---------------------------------------------------------------- diagnostic fill
__global__ void k_fill(void* out, int n, const int* flag){
  const int f32 = *flag;
  int i = blockIdx.x*256 + threadIdx.x;
  if(i<n) stout(out, i, 12345.0f, f32);
}

// ---------------------------------------------------------------- weight re-layout: wt[tap][oc][ci] (+ zero the halo source buffer)
__global__ void k_wprep(const void* __restrict__ cw, bf16* __restrict__ wt,
                        float* __restrict__ zbuf, const int* __restrict__ flag){
  const int f32 = *flag;
  if(blockIdx.x==0 && threadIdx.x<32) zbuf[threadIdx.x] = 0.f;   // 128B zeros for convm halo
  int t = blockIdx.x*256 + threadIdx.x;   // 110592 = 27*64*64
  if(t >= 27*64*64) return;
  int tap = t >> 12;          // /4096
  int oc  = (t >> 6) & 63;
  int ci  = t & 63;
  wt[t] = f2b(ldin(cw, ((size_t)(oc*64+ci))*27 + tap, f32));
}

// ---------------------------------------------------------------- in_proj as MFMA GEMM
__global__ __launch_bounds__(256) void k_inprojm(
    const void* __restrict__ in, const void* __restrict__ pw,
    bf16* __restrict__ xz, bf16* __restrict__ xin_t,
    const int* __restrict__ flag){
  const int f32 = *flag;
  __shared__ bf16 tok[128*72];   // [token][c], pitch 72
  __shared__ bf16 wl [128*72];   // [j][c],     pitch 72
  int tid = threadIdx.x;
  int b = blockIdx.x >> 8, tile = blockIdx.x & 255;
  int l0 = tile*128;

  for(int p=tid; p<1024; p+=256){          // weights: (j, c8)
    int j = p & 127, c8 = p >> 7;
    short8 v;
    #pragma unroll
    for(int k=0;k<8;k++){
      bf16 t = f2b(ldin(pw, j*64 + c8*8 + k, f32));
      v[k] = *(short*)&t;
    }
    *(short8*)(&wl[j*72 + c8*8]) = v;
  }
  for(int p=tid; p<1024; p+=256){          // tokens: (i, c8), coalesced over i
    int i = p & 127, c8 = p >> 7;
    short8 v;
    #pragma unroll
    for(int k=0;k<8;k++){
      bf16 t = f2b(ldin(in, ((size_t)(b*64 + c8*8 + k))*SP + l0 + i, f32));
      v[k] = *(short*)&t;
    }
    *(short8*)(&tok[i*72 + c8*8]) = v;
  }
  __syncthreads();

  int lane = tid & 63, wv = tid >> 6;
  int pn = lane & 15, quad = lane >> 4, kg8 = quad*8;
  f32x4 acc[2][8];
  #pragma unroll
  for(int mt=0;mt<2;mt++)
    #pragma unroll
    for(int nt=0;nt<8;nt++) acc[mt][nt]=(f32x4)(0.f);

  #pragma unroll
  for(int kq=0;kq<2;kq++){
    short8 a0 = *(const short8*)(&tok[(wv*32      + pn)*72 + kq*32 + kg8]);
    short8 a1 = *(const short8*)(&tok[(wv*32 + 16 + pn)*72 + kq*32 + kg8]);
    #pragma unroll
    for(int nt=0;nt<8;nt++){
      short8 bb = *(const short8*)(&wl[(nt*16+pn)*72 + kq*32 + kg8]);
      acc[0][nt] = __builtin_amdgcn_mfma_f32_16x16x32_bf16(a0,bb,acc[0][nt],0,0,0);
      acc[1][nt] = __builtin_amdgcn_mfma_f32_16x16x32_bf16(a1,bb,acc[1][nt],0,0,0);
    }
  }

  #pragma unroll
  for(int mt=0;mt<2;mt++){
    #pragma unroll
    for(int nt=0;nt<8;nt++){
      #pragma unroll
      for(int r=0;r<4;r++){
        int token = wv*32 + mt*16 + quad*4 + r;
        xz[((size_t)b*LTOK + l0 + token)*128 + nt*16 + pn] = f2b(acc[mt][nt][r]);
      }
    }
  }
  for(int p=tid; p<8192; p+=256){
    int i = p >> 6, c = p & 63;
    xin_t[((size_t)b*SP + l0 + i)*64 + c] = tok[i*72 + c];
  }
}

// ---------------------------------------------------------------- MFMA conv3d (both convs)
// R22: R20 tile (3h x 18w x 18d x 32ci, 64KB LDS, grid 1024, same staging map,
// same XOR-quad swizzle, same 32B d-half writes -- traffic PROVEN at 10/16.4MB)
// but 512-thread blocks: 8 waves x 2 w-rows each. LDS still allows 2 blocks/CU
// -> 16 waves/CU (2x R20's 8) with ZERO change to global access pattern.
// R19/R21 lesson: tile shrinks explode FETCH/WRITE 3-4x; tile is frozen.
__global__ __launch_bounds__(512, 2) void k_convm(
    const bf16* __restrict__ xin_t, const bf16* __restrict__ wt,
    const void* __restrict__ cb, const bf16* __restrict__ skip,
    bf16* __restrict__ out_bf, void* __restrict__ out_any,
    int mode, const int* __restrict__ flag, const float* __restrict__ zbuf){
  const int f32 = *flag;
  __shared__ bf16 xt[4096*8];  // 4096 16B-units = 65,536 B (972*4=3888 used + pad)

  int tid  = threadIdx.x;
  int lane = tid & 63;
  int wv   = tid >> 6;          // 0..7
  int pn   = lane & 15;
  int quad = lane >> 4;
  int kg8  = quad * 8;
  int laneA = pn*64 + kg8;

  int blk0 = blockIdx.x;                       // 1024 blocks
  int blk  = (blk0 & 7)*128 + (blk0 >> 3);     // bijective XCD-contiguous remap
  int ocg = blk & 3;
  int wh  = (blk >> 2) & 1;
  int dh2 = (blk >> 3) & 1;
  int h   = (blk >> 4) & 31;
  int b   = blk >> 9;
  int w0  = wh*16;
  int d0  = dh2*16;

  f32x4 acc[2];                 // [wr]
  acc[0]=(f32x4)(0.f); acc[1]=(f32x4)(0.f);

  for(int cic=0; cic<64; cic+=32){
    if(cic) __syncthreads();
    // stage 3h x 18w x 18d x 32ci via LDS-DMA; every unit (incl. pad) written
    {
      bf16* dstw = &xt[(size_t)(wv*64)*8];     // wave-uniform base, lane x 16B implicit
      for(int it=0; it<8; it++){
        int u = it*512 + tid;                  // physical 16B unit (linear)
        int row = u >> 2;
        int q4  = (u & 3) ^ ((u >> 3) & 3);    // inverse swizzle -> logical ci-quad
        int hh = row / 324; int rem = row - hh*324;
        int ww = rem / 18;  int dd = rem - ww*18;
        int hg = h + hh - 1, wg = w0 + ww - 1, d = d0 + dd - 1;
        bool ok = ((unsigned)hg < 32u) && ((unsigned)wg < 32u) && ((unsigned)d < 32u);
        const void* src = ok
          ? (const void*)&xin_t[(((size_t)b*SP) + hg*1024 + wg*32 + d)*64 + cic + q4*8]
          : (const void*)zbuf;
        __builtin_amdgcn_global_load_lds(
            (const __attribute__((address_space(1))) void*)src,
            (__attribute__((address_space(3))) void*)(dstw + (size_t)it*512*8),
            16, 0, 0);
      }
    }
    __syncthreads();

    // hoist all 27 taps' A-frags for this ocg+chunk into registers
    short8 afr[27];
    #pragma unroll
    for(int t=0;t<27;t++)
      afr[t] = *(const short8*)(wt + t*4096 + ocg*1024 + cic + laneA);

    #pragma unroll
    for(int kz=0;kz<3;kz++){
      #pragma unroll
      for(int ky=0;ky<3;ky++){
        #pragma unroll
        for(int kx=0;kx<3;kx++){
          int tap = (kz*3+ky)*3+kx;
          #pragma unroll
          for(int wr=0;wr<2;wr++){
            int rix = (kz*18 + wv*2 + wr + ky)*18 + kx + pn;
            int punit = rix*4 + (quad ^ ((rix>>1)&3));   // swizzled read
            short8 bb = *(const short8*)(&xt[(size_t)punit*8]);
            acc[wr] = __builtin_amdgcn_mfma_f32_16x16x32_bf16(afr[tap], bb, acc[wr], 0,0,0);
          }
        }
      }
    }
  }

  #pragma unroll
  for(int wr=0;wr<2;wr++){
    #pragma unroll
    for(int r=0;r<4;r++){
      int oc = ocg*16 + quad*4 + r;
      size_t idx = ((size_t)(b*64+oc))*SP + h*1024 + (w0 + wv*2 + wr)*32 + d0 + pn;
      float v = acc[wr][r] + ldin(cb, oc, f32);
      if(mode==0) out_bf[idx] = f2b(v);
      else        stout(out_any, idx, v + b2f(skip[idx]), f32);
    }
  }
}

// ---------------------------------------------------------------- instance norm + relu (in place, bf16)
__global__ void k_inorm(bf16* __restrict__ buf){
  int bc = blockIdx.x;
  bf16* p = buf + (size_t)bc*SP;
  float s=0.f, s2=0.f;
  for(int i=threadIdx.x;i<SP;i+=256){ float v=b2f(p[i]); s+=v; s2+=v*v; }
  __shared__ float sh[8];
  #pragma unroll
  for(int m=32;m>=1;m>>=1){ s += __shfl_xor(s,m); s2 += __shfl_xor(s2,m); }
  int wid = threadIdx.x>>6;
  if((threadIdx.x&63)==0){ sh[wid]=s; sh[4+wid]=s2; }
  __syncthreads();
  if(threadIdx.x==0){ float a=0,b2=0; for(int i=0;i<4;i++){a+=sh[i]; b2+=sh[4+i];} sh[0]=a; sh[4]=b2; }
  __syncthreads();
  float mean = sh[0]*(1.f/SP);
  float var  = sh[4]*(1.f/SP) - mean*mean;
  float inv = rsqrtf(fmaxf(var,0.f) + 1e-5f);
  for(int i=threadIdx.x;i<SP;i+=256){
    float v=(b2f(p[i])-mean)*inv;
    p[i] = f2b(v>0.f ? v : 0.f);
  }
}

// ---------------------------------------------------------------- per-direction prep: conv1d+silu, x_proj
// R14 structure; R18: rcp-silu.
__global__ __launch_bounds__(256) void k_dirprep(
                          const bf16* __restrict__ xz, const void* __restrict__ c1w,
                          const void* __restrict__ c1b, const void* __restrict__ xpw,
                          bf16* __restrict__ bcg, float* __restrict__ dtr,
                          const int* __restrict__ flag){
  const int f32 = *flag;
  __shared__ float xs[67][64];
  __shared__ float xcs[64][68];   // pitch 68 floats: 16B-aligned rows
  __shared__ float xws[20][68];
  int bid = blockIdx.x;
  int g = bid >> 10, b = (bid>>9)&1, tile = bid & 511;
  int l0 = tile*64;
  int gb = g*2+b;
  int tid = threadIdx.x;
  for(int t=tid; t<20*64; t+=256){ int j=t>>6, d=t&63; xws[j][d]=ldin(xpw, t, f32); }
  for(int t=tid; t<67*64; t+=256){
    int row=t>>6, d=t&63;
    int l = l0 + row - 3;
    float v = 0.f;
    if(l>=0 && l<LTOK){
      int lg = g ? (LTOK-1-l) : l;
      v = b2f(xz[((size_t)b*LTOK + lg)*128 + d]);
    }
    xs[row][d]=v;
  }
  __syncthreads();
  {
    int d = tid & 63;
    float cw0=ldin(c1w,d*4+0,f32), cw1=ldin(c1w,d*4+1,f32),
          cw2=ldin(c1w,d*4+2,f32), cw3=ldin(c1w,d*4+3,f32);
    float cb_=ldin(c1b,d,f32);
    for(int tl = tid>>6; tl<64; tl+=4){
      float acc = cb_ + cw0*xs[tl][d] + cw1*xs[tl+1][d] + cw2*xs[tl+2][d] + cw3*xs[tl+3][d];
      xcs[tl][d] = fsilu(acc);
    }
  }
  __syncthreads();
  {
    int tl = tid & 63, wq = tid >> 6;      // wave wq owns j = wq*5 .. wq*5+4
    float acc[5] = {0.f,0.f,0.f,0.f,0.f};
    #pragma unroll 4
    for(int d4=0; d4<16; d4++){
      float4 xv = *(const float4*)(&xcs[tl][d4*4]);
      #pragma unroll
      for(int jj=0; jj<5; jj++){
        float4 wv = *(const float4*)(&xws[wq*5+jj][d4*4]);   // wave-broadcast
        acc[jj] += xv.x*wv.x + xv.y*wv.y + xv.z*wv.z + xv.w*wv.w;
      }
    }
    size_t l = (size_t)gb*LTOK + l0 + tl;
    #pragma unroll
    for(int jj=0; jj<5; jj++){
      int j = wq*5 + jj;
      if(j<4) dtr[l*4 + j] = acc[jj];
      else    bcg[l*16 + (j-4)] = f2b(acc[jj]);
    }
  }
}

// ---------------------------------------------------------------- scan pass1: 2-wave n-split, exp-chain fast path (R18)
__global__ __launch_bounds__(128, 4) void k_scan1(
                        const bf16* __restrict__ xz, const float* __restrict__ dtr,
                        const bf16* __restrict__ bcg,
                        const void* __restrict__ c1w, const void* __restrict__ c1b,
                        const void* __restrict__ dpw, const void* __restrict__ dpb,
                        const void* __restrict__ alog, const void* __restrict__ ablog,
                        float* __restrict__ psP, float* __restrict__ psS,
                        const int* __restrict__ flag){
  const int f32 = *flag;
  int bid = blockIdx.x;              // 4096 = 2g * 2b * NC
  int lane = threadIdx.x & 63;
  int nh   = threadIdx.x >> 6;       // n-half (0 or 1)
  int chunk = bid & (NC-1);
  int b = (bid>>10)&1;
  int g = bid>>11;
  int gb = g*2+b;
  const void* al = g ? ablog : alog;
  float ac2[4];                      // exp2-ready: ac * log2(e)
  #pragma unroll
  for(int n=0;n<4;n++) ac2[n] = -LOG2E*__expf(ldin(al, lane*8 + nh*4 + n, f32));
  // A-structure detection: ac[n] ~ acb * (nh*4+n+1)  (exact for this model's A_log)
  float m0 = (float)(nh*4+1);
  float acb2 = ac2[0] / m0;
  bool okl = true;
  #pragma unroll
  for(int n=1;n<4;n++) okl = okl && (fabsf(ac2[n] - acb2*(m0+n)) <= 0.01f*fabsf(ac2[n]));
  const bool fastA = __all(okl);
  float cw0=ldin(c1w,lane*4+0,f32), cw1=ldin(c1w,lane*4+1,f32), cw2=ldin(c1w,lane*4+2,f32), cw3=ldin(c1w,lane*4+3,f32);
  float cb_=ldin(c1b,lane,f32);
  float dw0=ldin(dpw,lane*4+0,f32), dw1=ldin(dpw,lane*4+1,f32), dw2=ldin(dpw,lane*4+2,f32), dw3=ldin(dpw,lane*4+3,f32);
  float db_=ldin(dpb,lane,f32);
  float S[4];
  #pragma unroll
  for(int n=0;n<4;n++) S[n]=0.f;
  float Tsum = 0.f;
  int lt0 = chunk*CLEN;
  float x0,x1,x2;
  {
    float xr[3];
    #pragma unroll
    for(int j=0;j<3;j++){
      int lt = lt0-3+j;
      float v=0.f;
      if(lt>=0){ int lg = g ? (LTOK-1-lt) : lt; v=b2f(xz[((size_t)b*LTOK+lg)*128 + lane]); }
      xr[j]=v;
    }
    x0=xr[0]; x1=xr[1]; x2=xr[2];
  }
  for(int i0=0;i0<CLEN;i0+=8){
    bf16 xv[8]; float4 dv[8]; short4v bb[8];
    #pragma unroll
    for(int k=0;k<8;k++){
      int lt = lt0+i0+k;
      int lg = g ? (LTOK-1-lt) : lt;
      xv[k] = xz[((size_t)b*LTOK+lg)*128 + lane];
      size_t l = (size_t)gb*LTOK + lt;
      dv[k] = *(const float4*)(dtr + l*4);
      bb[k] = *(const short4v*)(bcg + l*16 + nh*4);
    }
    #pragma unroll
    for(int k=0;k<8;k++){
      float x3 = b2f(xv[k]);
      float pre = cb_ + cw0*x0 + cw1*x1 + cw2*x2 + cw3*x3;
      float xc = fsilu(pre);
      float v = db_ + dv[k].x*dw0 + dv[k].y*dw1 + dv[k].z*dw2 + dv[k].w*dw3;
      float e = fexp2(-LOG2E*fabsf(v));
      float dt = fmaxf(v,0.f) + __logf(1.f+e);
      Tsum += dt;
      float bx = dt*xc;
      float a[4];
      if(fastA){
        float e1 = fexp2(dt*acb2);
        if(nh==0){ a[0]=e1; a[1]=e1*e1; a[2]=a[1]*e1; a[3]=a[1]*a[1]; }
        else { float e2=e1*e1, e4=e2*e2; a[0]=e4*e1; a[1]=e4*e2; a[2]=a[1]*e1; a[3]=e4*e4; }
      }else{
        #pragma unroll
        for(int n=0;n<4;n++) a[n] = fexp2(dt*ac2[n]);
      }
      #pragma unroll
      for(int n=0;n<4;n++) S[n] = a[n]*S[n] + bx*s2f(bb[k][n]);
      x0=x1; x1=x2; x2=x3;
    }
  }
  int seq = (gb*64 + lane)*8 + nh*4;
  #pragma unroll
  for(int n=0;n<4;n++){
    psP[(size_t)chunk*NSEQ + seq + n] = fexp2(ac2[n]*Tsum);
    psS[(size_t)chunk*NSEQ + seq + n] = S[n];
  }
}

// ---------------------------------------------------------------- scan pass2: hierarchical (depth 1024 -> 32/32/32)
__global__ void k_scan2a(const float* __restrict__ psP, const float* __restrict__ psS,
                         float* __restrict__ segP, float* __restrict__ segS){
  int idx = blockIdx.x*256 + threadIdx.x;       // 65536 = NSEQ*SEG
  int seq = idx & (NSEQ-1);
  int seg = idx >> 11;
  float P = 1.f, S = 0.f;
  int i0 = seg*SEGLEN;
  #pragma unroll 4
  for(int i=0;i<SEGLEN;i++){
    float p = psP[(size_t)(i0+i)*NSEQ + seq];
    float s = psS[(size_t)(i0+i)*NSEQ + seq];
    S = p*S + s;
    P *= p;
  }
  segP[seg*NSEQ + seq] = P;
  segS[seg*NSEQ + seq] = S;
}
__global__ void k_scan2b(const float* __restrict__ segP, const float* __restrict__ segS,
                         float* __restrict__ segC){
  int seq = blockIdx.x*256 + threadIdx.x;
  if(seq >= NSEQ) return;
  float h = 0.f;
  #pragma unroll
  for(int s=0;s<SEG;s++){
    segC[s*NSEQ + seq] = h;
    h = segP[s*NSEQ + seq]*h + segS[s*NSEQ + seq];
  }
}
__global__ void k_scan2c(const float* __restrict__ psP, const float* __restrict__ segC,
                         float* __restrict__ psC){
  int idx = blockIdx.x*256 + threadIdx.x;
  int seq = idx & (NSEQ-1);
  int seg = idx >> 11;
  float h = segC[seg*NSEQ + seq];
  int i0 = seg*SEGLEN;
  #pragma unroll 4
  for(int i=0;i<SEGLEN;i++){
    float p = psP[(size_t)(i0+i)*NSEQ + seq];
    float s = psC[(size_t)(i0+i)*NSEQ + seq];   // read partial BEFORE overwrite
    psC[(size_t)(i0+i)*NSEQ + seq] = h;
    h = p*h + s;
  }
}

// ---------------------------------------------------------------- scan pass3: 2-wave n-split, LDS y-combine, exp-chain fast path (R18)
__global__ __launch_bounds__(128, 4) void k_scan3(
                        const bf16* __restrict__ xz, const float* __restrict__ dtr,
                        const bf16* __restrict__ bcg,
                        const void* __restrict__ c1w, const void* __restrict__ c1b,
                        const void* __restrict__ dpw, const void* __restrict__ dpb,
                        const void* __restrict__ alog, const void* __restrict__ ablog,
                        const void* __restrict__ dskip, const float* __restrict__ carry,
                        bf16* __restrict__ ybuf, const int* __restrict__ flag){
  const int f32 = *flag;
  __shared__ float ysh[2][8][64];    // 4 KB double buffer
  int bid = blockIdx.x;              // 4096
  int lane = threadIdx.x & 63;
  int nh   = threadIdx.x >> 6;
  int chunk = bid & (NC-1);
  int b = (bid>>10)&1;
  int g = bid>>11;
  int gb = g*2+b;
  const void* al = g ? ablog : alog;
  float ac2[4];
  #pragma unroll
  for(int n=0;n<4;n++) ac2[n] = -LOG2E*__expf(ldin(al, lane*8 + nh*4 + n, f32));
  float m0 = (float)(nh*4+1);
  float acb2 = ac2[0] / m0;
  bool okl = true;
  #pragma unroll
  for(int n=1;n<4;n++) okl = okl && (fabsf(ac2[n] - acb2*(m0+n)) <= 0.01f*fabsf(ac2[n]));
  const bool fastA = __all(okl);
  float cw0=ldin(c1w,lane*4+0,f32), cw1=ldin(c1w,lane*4+1,f32), cw2=ldin(c1w,lane*4+2,f32), cw3=ldin(c1w,lane*4+3,f32);
  float cb_=ldin(c1b,lane,f32);
  float dw0=ldin(dpw,lane*4+0,f32), dw1=ldin(dpw,lane*4+1,f32), dw2=ldin(dpw,lane*4+2,f32), dw3=ldin(dpw,lane*4+3,f32);
  float db_=ldin(dpb,lane,f32);
  float dsk = ldin(dskip,lane,f32);
  int seq = (gb*64 + lane)*8 + nh*4;
  float h[4];
  #pragma unroll
  for(int n=0;n<4;n++) h[n] = carry[(size_t)chunk*NSEQ + seq + n];
  int lt0 = chunk*CLEN;
  float x0,x1,x2;
  {
    float xr[3];
    #pragma unroll
    for(int j=0;j<3;j++){
      int lt = lt0-3+j;
      float v=0.f;
      if(lt>=0){ int lg = g ? (LTOK-1-lt) : lt; v=b2f(xz[((size_t)b*LTOK+lg)*128 + lane]); }
      xr[j]=v;
    }
    x0=xr[0]; x1=xr[1]; x2=xr[2];
  }
  for(int i0=0;i0<CLEN;i0+=8){
    int bt = (i0>>3)&1;
    bf16 xv[8]; float4 dv[8]; short4v bb[8], cc[8];
    #pragma unroll
    for(int k=0;k<8;k++){
      int lt = lt0+i0+k;
      int lg = g ? (LTOK-1-lt) : lt;
      xv[k] = xz[((size_t)b*LTOK+lg)*128 + lane];
      size_t l = (size_t)gb*LTOK + lt;
      dv[k] = *(const float4*)(dtr + l*4);
      bb[k] = *(const short4v*)(bcg + l*16 + nh*4);
      cc[k] = *(const short4v*)(bcg + l*16 + 8 + nh*4);
    }
    float py[8];
    #pragma unroll
    for(int k=0;k<8;k++){
      float x3 = b2f(xv[k]);
      float pre = cb_ + cw0*x0 + cw1*x1 + cw2*x2 + cw3*x3;
      float xc = fsilu(pre);
      float v = db_ + dv[k].x*dw0 + dv[k].y*dw1 + dv[k].z*dw2 + dv[k].w*dw3;
      float e = fexp2(-LOG2E*fabsf(v));
      float dt = fmaxf(v,0.f) + __logf(1.f+e);
      float bx = dt*xc;
      float part = nh ? xc*dsk : 0.f;
      float a[4];
      if(fastA){
        float e1 = fexp2(dt*acb2);
        if(nh==0){ a[0]=e1; a[1]=e1*e1; a[2]=a[1]*e1; a[3]=a[1]*a[1]; }
        else { float e2=e1*e1, e4=e2*e2; a[0]=e4*e1; a[1]=e4*e2; a[2]=a[1]*e1; a[3]=e4*e4; }
      }else{
        #pragma unroll
        for(int n=0;n<4;n++) a[n] = fexp2(dt*ac2[n]);
      }
      #pragma unroll
      for(int n=0;n<4;n++){
        h[n] = a[n]*h[n] + bx*s2f(bb[k][n]);
        part += h[n]*s2f(cc[k][n]);
      }
      if(nh==0) ysh[bt][k][lane] = part;
      else      py[k] = part;
      x0=x1; x1=x2; x2=x3;
    }
    __syncthreads();
    if(nh==1){
      #pragma unroll
      for(int k=0;k<8;k++){
        size_t l = (size_t)gb*LTOK + lt0+i0+k;
        ybuf[l*64 + lane] = f2b(ysh[bt][k][lane] + py[k]);
      }
    }
  }
}

// ---------------------------------------------------------------- combine dirs * silu(z) + out_proj (MFMA) + LN -> vol (token-major)
__global__ __launch_bounds__(256) void k_outln(
                        const bf16* __restrict__ ybuf, const bf16* __restrict__ xz,
                        const void* __restrict__ opw,
                        const void* __restrict__ lng, const void* __restrict__ lnb,
                        bf16* __restrict__ vol_t, const int* __restrict__ flag){
  const int f32 = *flag;
  __shared__ bf16 vsm[64*72];   // [token][d] pitch 72; reused for LN output staging
  __shared__ bf16 wsm[64*72];   // [c][d]     pitch 72
  __shared__ float gsm[64], bsm[64];
  int tid = threadIdx.x;
  int b = blockIdx.x >> 9, tile = blockIdx.x & 511;
  int l0 = tile*64;

  for(int p=tid; p<512; p+=256){           // weights (c, d8)
    int c = p & 63, d8 = p >> 6;
    short8 v;
    #pragma unroll
    for(int k=0;k<8;k++){ bf16 t = f2b(ldin(opw, c*64 + d8*8 + k, f32)); v[k] = *(short*)&t; }
    *(short8*)(&wsm[c*72 + d8*8]) = v;
  }
  if(tid<64){ gsm[tid]=ldin(lng,tid,f32); bsm[tid]=ldin(lnb,tid,f32); }
  for(int p=tid; p<4096; p+=256){          // v = 0.5(yf+yb)*silu(z)
    int tl = p >> 6, d = p & 63;
    int l = l0 + tl;
    float yf = b2f(ybuf[((size_t)(0+b)*LTOK + l)*64 + d]);
    float yb = b2f(ybuf[((size_t)(2+b)*LTOK + (LTOK-1-l))*64 + d]);
    float z  = b2f(xz[((size_t)b*LTOK + l)*128 + 64 + d]);
    vsm[tl*72 + d] = f2b(0.5f*(yf+yb)*fsilu(z));
  }
  __syncthreads();

  int lane = tid & 63, wv = tid >> 6, pn = lane & 15, quad = lane >> 4, kg8 = quad*8;
  f32x4 acc[4];
  #pragma unroll
  for(int nt=0;nt<4;nt++) acc[nt]=(f32x4)(0.f);
  #pragma unroll
  for(int kq=0;kq<2;kq++){
    short8 a = *(const short8*)(&vsm[(wv*16+pn)*72 + kq*32 + kg8]);
    #pragma unroll
    for(int nt=0;nt<4;nt++){
      short8 bb = *(const short8*)(&wsm[(nt*16+pn)*72 + kq*32 + kg8]);
      acc[nt] = __builtin_amdgcn_mfma_f32_16x16x32_bf16(a,bb,acc[nt],0,0,0);
    }
  }
  __syncthreads();   // all reads of vsm done; safe to overwrite below

  float gl[4], bl[4];
  #pragma unroll
  for(int nt=0;nt<4;nt++){ gl[nt]=gsm[nt*16+pn]; bl[nt]=bsm[nt*16+pn]; }
  #pragma unroll
  for(int r=0;r<4;r++){
    float vals[4]; float s=0.f;
    #pragma unroll
    for(int nt=0;nt<4;nt++){ vals[nt]=acc[nt][r]; s+=vals[nt]; }
    #pragma unroll
    for(int m=1;m<16;m<<=1) s += __shfl_xor(s, m);
    float mu = s*(1.f/64.f);
    float s2=0.f;
    #pragma unroll
    for(int nt=0;nt<4;nt++){ float dv=vals[nt]-mu; s2+=dv*dv; }
    #pragma unroll
    for(int m=1;m<16;m<<=1) s2 += __shfl_xor(s2, m);
    float inv = rsqrtf(s2*(1.f/64.f) + 1e-5f);
    int token = wv*16 + quad*4 + r;
    #pragma unroll
    for(int nt=0;nt<4;nt++){
      vsm[token*72 + nt*16 + pn] = f2b((vals[nt]-mu)*inv*gl[nt] + bl[nt]);
    }
  }
  __syncthreads();
  for(int p=tid; p<512; p+=256){           // coalesced token-major short8 stores
    int tl = p >> 3, d8 = p & 7;
    *(short8*)(&vol_t[((size_t)b*SP + l0 + tl)*64 + d8*8]) = *(const short8*)(&vsm[tl*72 + d8*8]);
  }
}

// ---------------------------------------------------------------- launch
extern "C" void kernel_launch(void* const* d_in, const int* in_sizes, int n_in,
                              void* d_out, int out_size, void* d_ws, size_t ws_size,
                              hipStream_t stream){
  const void* input  = d_in[0];
  const void* conv_w = d_in[1];
  const void* conv_b = d_in[2];
  const void* inpw   = d_in[3];
  const void* c1w    = d_in[4];
  const void* c1b    = d_in[5];
  const void* xpw    = d_in[6];
  const void* dpw    = d_in[7];
  const void* dpb    = d_in[8];
  const void* alog   = d_in[9];
  const void* ablog  = d_in[10];
  const void* dskip  = d_in[11];
  const void* opw    = d_in[12];
  const void* lng    = d_in[13];
  const void* lnb    = d_in[14];

  // R14 layout (NC=1024): psP/psS 8.4 MB; aliasing keeps NEED < 58 MB.
  //   ybuf (16.8M) aliases psP(8.4M)+xin_t(8.4M)  [both dead before scan3 writes ybuf]
  //   vol_t (8.4M) aliases psS                    [carry dead after scan3]
  char* base = (char*)d_ws;
  bf16*  skipb = (bf16*) (base + 0);            //  8,388,608 B
  bf16*  xz    = (bf16*) (base + 8388608);      // 16,777,216 B -> 25,165,824
  bf16*  bcg   = (bf16*) (base + 25165824);     //  4,194,304 B -> 29,360,128
  float* dtr   = (float*)(base + 29360128);     //  2,097,152 B -> 31,457,280
  float* psP   = (float*)(base + 31457280);     //  8,388,608 B -> 39,845,888 (NC*NSEQ*4)
  bf16*  xin_t = (bf16*) (base + 39845888);     //  8,388,608 B -> 48,234,496 (alias ybuf-hi)
  bf16*  ybuf  = (bf16*) (base + 31457280);     // 16,777,216 B alias psP+xin_t
  float* psS   = (float*)(base + 48234496);     //  8,388,608 B -> 56,623,104 (carry; vol_t alias)
  bf16*  vol_t = (bf16*) (base + 48234496);     //  8,388,608 B alias psS
  bf16*  wt    = (bf16*) (base + 56623104);     //    221,184 B -> 56,844,288
  float* segP  = (float*)(base + 56844288);     //    262,144 B -> 57,106,432
  float* segS  = (float*)(base + 57106432);     //    262,144 B -> 57,368,576
  float* segC  = (float*)(base + 57368576);     //    262,144 B -> 57,630,720
  int*   flagp = (int*)  (base + 57630720);     //  16 B -> 57,630,736
  float* zbuf  = (float*)(base + 57630736);     //  128 B zeros (convm halo source)
  const size_t NEED = 57630864;

  k_detect<<<dim3(1), dim3(64), 0, stream>>>(conv_w, flagp);

  if(ws_size < NEED){
    k_fill<<<dim3((out_size+255)/256), dim3(256), 0, stream>>>(d_out, out_size, flagp);
    return;
  }

  k_wprep  <<<dim3(432),   dim3(256), 0, stream>>>(conv_w, wt, zbuf, flagp);
  k_inprojm<<<dim3(512),   dim3(256), 0, stream>>>(input, inpw, xz, xin_t, flagp);
  // conv #1: xin_t -> skipb (bf16, channel-major out)
  k_convm  <<<dim3(1024),  dim3(512), 0, stream>>>(xin_t, wt, conv_b, nullptr, skipb, nullptr, 0, flagp, zbuf);
  k_inorm  <<<dim3(128),   dim3(256), 0, stream>>>(skipb);
  k_dirprep<<<dim3(2048),  dim3(256), 0, stream>>>(xz, c1w, c1b, xpw, bcg, dtr, flagp);
  k_scan1  <<<dim3(4096),  dim3(128), 0, stream>>>(xz, dtr, bcg, c1w, c1b, dpw, dpb, alog, ablog, psP, psS, flagp);
  k_scan2a <<<dim3(256),   dim3(256), 0, stream>>>(psP, psS, segP, segS);
  k_scan2b <<<dim3(8),     dim3(256), 0, stream>>>(segP, segS, segC);
  k_scan2c <<<dim3(256),   dim3(256), 0, stream>>>(psP, segC, psS);
  k_scan3  <<<dim3(4096),  dim3(128), 0, stream>>>(xz, dtr, bcg, c1w, c1b, dpw, dpb, alog, ablog, dskip, psS, ybuf, flagp);
  k_outln  <<<dim3(1024),  dim3(256), 0, stream>>>(ybuf, xz, opw, lng, lnb, vol_t, flagp);
  // conv #2: vol_t (+skipb) -> d_out, dual-dtype out
  k_convm  <<<dim3(1024),  dim3(512), 0, stream>>>(vol_t, wt, conv_b, skipb, nullptr, d_out, 1, flagp, zbuf);
}

// Round 15
// 393.534 us; speedup vs baseline: 1.1417x; 1.1046x over previous
//
#include <hip/hip_runtime.h>
#include <hip/hip_bf16.h>

typedef __hip_bfloat16 bf16;
typedef __attribute__((ext_vector_type(8))) short short8;   // 8 bf16 = 4 VGPRs
typedef __attribute__((ext_vector_type(4))) short short4v;  // 4 bf16 = 2 VGPRs
typedef __attribute__((ext_vector_type(4))) float f32x4;    // MFMA acc

__device__ __forceinline__ float b2f(bf16 x){ return __bfloat162float(x); }
__device__ __forceinline__ bf16  f2b(float x){ return __float2bfloat16(x); }
__device__ __forceinline__ float s2f(short s){ bf16 t = *(bf16*)&s; return b2f(t); }

#define LOG2E 1.4426950408889634f

// raw v_exp_f32 (computes 2^x)
__device__ __forceinline__ float fexp2(float x){ return __builtin_amdgcn_exp2f(x); }

// fast silu: x * rcp(1+e^-x)  (v_rcp_f32, ~1ulp -- fine at bf16 output precision)
__device__ __forceinline__ float fsilu(float x){
  return x * __builtin_amdgcn_rcpf(1.f + fexp2(-LOG2E*x));
}

// dual-dtype input load / output store (flag: 1 = fp32 storage, 0 = bf16)
__device__ __forceinline__ float ldin(const void* p, size_t i, int f32){
  return f32 ? ((const float*)p)[i] : b2f(((const bf16*)p)[i]);
}
__device__ __forceinline__ void stout(void* p, size_t i, float v, int f32){
  if(f32) ((float*)p)[i] = v; else ((bf16*)p)[i] = f2b(v);
}

constexpr int SP   = 32*32*32;   // 32768 spatial per (b,c)
constexpr int LTOK = SP;         // tokens per batch
constexpr int NC   = 1024;       // scan chunks
constexpr int CLEN = LTOK / NC;  // 32
constexpr int NSEQ = 2*2*64*8;   // 2048 scan sequences (dir,b,d,n)
constexpr int SEG  = 32;         // scan2 hierarchy: 32 segments x 32 chunks
constexpr int SEGLEN = NC/SEG;   // 32

// ---------------------------------------------------------------- dtype detector
__global__ void k_detect(const void* conv_w, int* flag){
  if(threadIdx.x==0 && blockIdx.x==0){
    const bf16* p = (const bf16*)conv_w;
    int f = 0;
    for(int i=0;i<128;i++){
      float v = b2f(p[i]);
      if(!(v==v) || fabsf(v) > 1.0f) f = 1;   // bf16 weights are 0.05-scale
    }
    *flag = f;
  }
}

// ---------------------------------------------------------------- diagnostic fill
__global__ void k_fill(void* out, int n, const int* flag){
  const int f32 = *flag;
  int i = blockIdx.x*256 + threadIdx.x;
  if(i<n) stout(out, i, 12345.0f, f32);
}

// ---------------------------------------------------------------- weight re-layout: wt[tap][oc][ci] (+ zero the halo source buffer)
__global__ void k_wprep(const void* __restrict__ cw, bf16* __restrict__ wt,
                        float* __restrict__ zbuf, const int* __restrict__ flag){
  const int f32 = *flag;
  if(blockIdx.x==0 && threadIdx.x<32) zbuf[threadIdx.x] = 0.f;   // 128B zeros for convm halo
  int t = blockIdx.x*256 + threadIdx.x;   // 110592 = 27*64*64
  if(t >= 27*64*64) return;
  int tap = t >> 12;          // /4096
  int oc  = (t >> 6) & 63;
  int ci  = t & 63;
  wt[t] = f2b(ldin(cw, ((size_t)(oc*64+ci))*27 + tap, f32));
}

// ---------------------------------------------------------------- in_proj as MFMA GEMM
__global__ __launch_bounds__(256) void k_inprojm(
    const void* __restrict__ in, const void* __restrict__ pw,
    bf16* __restrict__ xz, bf16* __restrict__ xin_t,
    const int* __restrict__ flag){
  const int f32 = *flag;
  __shared__ bf16 tok[128*72];   // [token][c], pitch 72
  __shared__ bf16 wl [128*72];   // [j][c],     pitch 72
  int tid = threadIdx.x;
  int b = blockIdx.x >> 8, tile = blockIdx.x & 255;
  int l0 = tile*128;

  for(int p=tid; p<1024; p+=256){          // weights: (j, c8)
    int j = p & 127, c8 = p >> 7;
    short8 v;
    #pragma unroll
    for(int k=0;k<8;k++){
      bf16 t = f2b(ldin(pw, j*64 + c8*8 + k, f32));
      v[k] = *(short*)&t;
    }
    *(short8*)(&wl[j*72 + c8*8]) = v;
  }
  for(int p=tid; p<1024; p+=256){          // tokens: (i, c8), coalesced over i
    int i = p & 127, c8 = p >> 7;
    short8 v;
    #pragma unroll
    for(int k=0;k<8;k++){
      bf16 t = f2b(ldin(in, ((size_t)(b*64 + c8*8 + k))*SP + l0 + i, f32));
      v[k] = *(short*)&t;
    }
    *(short8*)(&tok[i*72 + c8*8]) = v;
  }
  __syncthreads();

  int lane = tid & 63, wv = tid >> 6;
  int pn = lane & 15, quad = lane >> 4, kg8 = quad*8;
  f32x4 acc[2][8];
  #pragma unroll
  for(int mt=0;mt<2;mt++)
    #pragma unroll
    for(int nt=0;nt<8;nt++) acc[mt][nt]=(f32x4)(0.f);

  #pragma unroll
  for(int kq=0;kq<2;kq++){
    short8 a0 = *(const short8*)(&tok[(wv*32      + pn)*72 + kq*32 + kg8]);
    short8 a1 = *(const short8*)(&tok[(wv*32 + 16 + pn)*72 + kq*32 + kg8]);
    #pragma unroll
    for(int nt=0;nt<8;nt++){
      short8 bb = *(const short8*)(&wl[(nt*16+pn)*72 + kq*32 + kg8]);
      acc[0][nt] = __builtin_amdgcn_mfma_f32_16x16x32_bf16(a0,bb,acc[0][nt],0,0,0);
      acc[1][nt] = __builtin_amdgcn_mfma_f32_16x16x32_bf16(a1,bb,acc[1][nt],0,0,0);
    }
  }

  #pragma unroll
  for(int mt=0;mt<2;mt++){
    #pragma unroll
    for(int nt=0;nt<8;nt++){
      #pragma unroll
      for(int r=0;r<4;r++){
        int token = wv*32 + mt*16 + quad*4 + r;
        xz[((size_t)b*LTOK + l0 + token)*128 + nt*16 + pn] = f2b(acc[mt][nt][r]);
      }
    }
  }
  for(int p=tid; p<8192; p+=256){
    int i = p >> 6, c = p & 63;
    xin_t[((size_t)b*SP + l0 + i)*64 + c] = tok[i*72 + c];
  }
}

// ---------------------------------------------------------------- MFMA conv3d (both convs)
// R23 = R20 (proven 53.6us steady): staging via global_load_lds (width 16).
// LDS: linear 16B units, pitch 32 (64B rows), XOR-quad bank swizzle (involution,
// applied on per-lane global source during staging and on MFMA-read address).
// Halo lanes source a zero buffer. 64KB LDS, 2 blocks/CU, d-half tile.
// Experiment ledger (frozen): DMA-staging WIN, swizzle WIN, 32-oc neutral,
// d-quarter -21us (FETCH/WRITE 4.5x), w-split -25us (3x), 8-wave -21us
// (occupancy didn't materialize; traffic flat). Structure is local-optimal;
// further gains need inline-asm counted-vmcnt pipelining.
__global__ __launch_bounds__(256, 2) void k_convm(
    const bf16* __restrict__ xin_t, const bf16* __restrict__ wt,
    const void* __restrict__ cb, const bf16* __restrict__ skip,
    bf16* __restrict__ out_bf, void* __restrict__ out_any,
    int mode, const int* __restrict__ flag, const float* __restrict__ zbuf){
  const int f32 = *flag;
  __shared__ bf16 xt[4096*8];  // 4096 16B-units = 65,536 B (972*4=3888 used + pad)

  int tid  = threadIdx.x;
  int lane = tid & 63;
  int wv   = tid >> 6;
  int pn   = lane & 15;
  int quad = lane >> 4;
  int kg8  = quad * 8;
  int laneA = pn*64 + kg8;

  int blk0 = blockIdx.x;                       // 1024 blocks
  int blk  = (blk0 & 7)*128 + (blk0 >> 3);     // bijective XCD-contiguous remap
  int ocg = blk & 3;
  int wh  = (blk >> 2) & 1;
  int dh2 = (blk >> 3) & 1;
  int h   = (blk >> 4) & 31;
  int b   = blk >> 9;
  int w0  = wh*16;
  int d0  = dh2*16;

  f32x4 acc[4];                 // [wr]
  #pragma unroll
  for(int m=0;m<4;m++) acc[m]=(f32x4)(0.f);

  for(int cic=0; cic<64; cic+=32){
    if(cic) __syncthreads();
    // stage 3h x 18w x 18d x 32ci via LDS-DMA; every unit (incl. pad) written
    {
      bf16* dstw = &xt[(size_t)(wv*64)*8];     // wave-uniform base, lane x 16B implicit
      for(int it=0; it<16; it++){
        int u = it*256 + tid;                  // physical 16B unit (linear)
        int row = u >> 2;
        int q4  = (u & 3) ^ ((u >> 3) & 3);    // inverse swizzle -> logical ci-quad
        int hh = row / 324; int rem = row - hh*324;
        int ww = rem / 18;  int dd = rem - ww*18;
        int hg = h + hh - 1, wg = w0 + ww - 1, d = d0 + dd - 1;
        bool ok = ((unsigned)hg < 32u) && ((unsigned)wg < 32u) && ((unsigned)d < 32u);
        const void* src = ok
          ? (const void*)&xin_t[(((size_t)b*SP) + hg*1024 + wg*32 + d)*64 + cic + q4*8]
          : (const void*)zbuf;
        __builtin_amdgcn_global_load_lds(
            (const __attribute__((address_space(1))) void*)src,
            (__attribute__((address_space(3))) void*)(dstw + (size_t)it*256*8),
            16, 0, 0);
      }
    }
    __syncthreads();

    // hoist all 27 taps' A-frags for this ocg+chunk into registers
    short8 afr[27];
    #pragma unroll
    for(int t=0;t<27;t++)
      afr[t] = *(const short8*)(wt + t*4096 + ocg*1024 + cic + laneA);

    #pragma unroll
    for(int kz=0;kz<3;kz++){
      #pragma unroll
      for(int ky=0;ky<3;ky++){
        #pragma unroll
        for(int kx=0;kx<3;kx++){
          int tap = (kz*3+ky)*3+kx;
          #pragma unroll
          for(int wr=0;wr<4;wr++){
            int rix = (kz*18 + wv*4 + wr + ky)*18 + kx + pn;
            int punit = rix*4 + (quad ^ ((rix>>1)&3));   // swizzled read
            short8 bb = *(const short8*)(&xt[(size_t)punit*8]);
            acc[wr] = __builtin_amdgcn_mfma_f32_16x16x32_bf16(afr[tap], bb, acc[wr], 0,0,0);
          }
        }
      }
    }
  }

  #pragma unroll
  for(int wr=0;wr<4;wr++){
    #pragma unroll
    for(int r=0;r<4;r++){
      int oc = ocg*16 + quad*4 + r;
      size_t idx = ((size_t)(b*64+oc))*SP + h*1024 + (w0 + wv*4 + wr)*32 + d0 + pn;
      float v = acc[wr][r] + ldin(cb, oc, f32);
      if(mode==0) out_bf[idx] = f2b(v);
      else        stout(out_any, idx, v + b2f(skip[idx]), f32);
    }
  }
}

// ---------------------------------------------------------------- instance norm + relu (in place, bf16)
__global__ void k_inorm(bf16* __restrict__ buf){
  int bc = blockIdx.x;
  bf16* p = buf + (size_t)bc*SP;
  float s=0.f, s2=0.f;
  for(int i=threadIdx.x;i<SP;i+=256){ float v=b2f(p[i]); s+=v; s2+=v*v; }
  __shared__ float sh[8];
  #pragma unroll
  for(int m=32;m>=1;m>>=1){ s += __shfl_xor(s,m); s2 += __shfl_xor(s2,m); }
  int wid = threadIdx.x>>6;
  if((threadIdx.x&63)==0){ sh[wid]=s; sh[4+wid]=s2; }
  __syncthreads();
  if(threadIdx.x==0){ float a=0,b2=0; for(int i=0;i<4;i++){a+=sh[i]; b2+=sh[4+i];} sh[0]=a; sh[4]=b2; }
  __syncthreads();
  float mean = sh[0]*(1.f/SP);
  float var  = sh[4]*(1.f/SP) - mean*mean;
  float inv = rsqrtf(fmaxf(var,0.f) + 1e-5f);
  for(int i=threadIdx.x;i<SP;i+=256){
    float v=(b2f(p[i])-mean)*inv;
    p[i] = f2b(v>0.f ? v : 0.f);
  }
}

// ---------------------------------------------------------------- per-direction prep: conv1d+silu, x_proj
// R14 structure; R18: rcp-silu.
__global__ __launch_bounds__(256) void k_dirprep(
                          const bf16* __restrict__ xz, const void* __restrict__ c1w,
                          const void* __restrict__ c1b, const void* __restrict__ xpw,
                          bf16* __restrict__ bcg, float* __restrict__ dtr,
                          const int* __restrict__ flag){
  const int f32 = *flag;
  __shared__ float xs[67][64];
  __shared__ float xcs[64][68];   // pitch 68 floats: 16B-aligned rows
  __shared__ float xws[20][68];
  int bid = blockIdx.x;
  int g = bid >> 10, b = (bid>>9)&1, tile = bid & 511;
  int l0 = tile*64;
  int gb = g*2+b;
  int tid = threadIdx.x;
  for(int t=tid; t<20*64; t+=256){ int j=t>>6, d=t&63; xws[j][d]=ldin(xpw, t, f32); }
  for(int t=tid; t<67*64; t+=256){
    int row=t>>6, d=t&63;
    int l = l0 + row - 3;
    float v = 0.f;
    if(l>=0 && l<LTOK){
      int lg = g ? (LTOK-1-l) : l;
      v = b2f(xz[((size_t)b*LTOK + lg)*128 + d]);
    }
    xs[row][d]=v;
  }
  __syncthreads();
  {
    int d = tid & 63;
    float cw0=ldin(c1w,d*4+0,f32), cw1=ldin(c1w,d*4+1,f32),
          cw2=ldin(c1w,d*4+2,f32), cw3=ldin(c1w,d*4+3,f32);
    float cb_=ldin(c1b,d,f32);
    for(int tl = tid>>6; tl<64; tl+=4){
      float acc = cb_ + cw0*xs[tl][d] + cw1*xs[tl+1][d] + cw2*xs[tl+2][d] + cw3*xs[tl+3][d];
      xcs[tl][d] = fsilu(acc);
    }
  }
  __syncthreads();
  {
    int tl = tid & 63, wq = tid >> 6;      // wave wq owns j = wq*5 .. wq*5+4
    float acc[5] = {0.f,0.f,0.f,0.f,0.f};
    #pragma unroll 4
    for(int d4=0; d4<16; d4++){
      float4 xv = *(const float4*)(&xcs[tl][d4*4]);
      #pragma unroll
      for(int jj=0; jj<5; jj++){
        float4 wv = *(const float4*)(&xws[wq*5+jj][d4*4]);   // wave-broadcast
        acc[jj] += xv.x*wv.x + xv.y*wv.y + xv.z*wv.z + xv.w*wv.w;
      }
    }
    size_t l = (size_t)gb*LTOK + l0 + tl;
    #pragma unroll
    for(int jj=0; jj<5; jj++){
      int j = wq*5 + jj;
      if(j<4) dtr[l*4 + j] = acc[jj];
      else    bcg[l*16 + (j-4)] = f2b(acc[jj]);
    }
  }
}

// ---------------------------------------------------------------- scan pass1: 2-wave n-split, exp-chain fast path (R18)
__global__ __launch_bounds__(128, 4) void k_scan1(
                        const bf16* __restrict__ xz, const float* __restrict__ dtr,
                        const bf16* __restrict__ bcg,
                        const void* __restrict__ c1w, const void* __restrict__ c1b,
                        const void* __restrict__ dpw, const void* __restrict__ dpb,
                        const void* __restrict__ alog, const void* __restrict__ ablog,
                        float* __restrict__ psP, float* __restrict__ psS,
                        const int* __restrict__ flag){
  const int f32 = *flag;
  int bid = blockIdx.x;              // 4096 = 2g * 2b * NC
  int lane = threadIdx.x & 63;
  int nh   = threadIdx.x >> 6;       // n-half (0 or 1)
  int chunk = bid & (NC-1);
  int b = (bid>>10)&1;
  int g = bid>>11;
  int gb = g*2+b;
  const void* al = g ? ablog : alog;
  float ac2[4];                      // exp2-ready: ac * log2(e)
  #pragma unroll
  for(int n=0;n<4;n++) ac2[n] = -LOG2E*__expf(ldin(al, lane*8 + nh*4 + n, f32));
  // A-structure detection: ac[n] ~ acb * (nh*4+n+1)  (exact for this model's A_log)
  float m0 = (float)(nh*4+1);
  float acb2 = ac2[0] / m0;
  bool okl = true;
  #pragma unroll
  for(int n=1;n<4;n++) okl = okl && (fabsf(ac2[n] - acb2*(m0+n)) <= 0.01f*fabsf(ac2[n]));
  const bool fastA = __all(okl);
  float cw0=ldin(c1w,lane*4+0,f32), cw1=ldin(c1w,lane*4+1,f32), cw2=ldin(c1w,lane*4+2,f32), cw3=ldin(c1w,lane*4+3,f32);
  float cb_=ldin(c1b,lane,f32);
  float dw0=ldin(dpw,lane*4+0,f32), dw1=ldin(dpw,lane*4+1,f32), dw2=ldin(dpw,lane*4+2,f32), dw3=ldin(dpw,lane*4+3,f32);
  float db_=ldin(dpb,lane,f32);
  float S[4];
  #pragma unroll
  for(int n=0;n<4;n++) S[n]=0.f;
  float Tsum = 0.f;
  int lt0 = chunk*CLEN;
  float x0,x1,x2;
  {
    float xr[3];
    #pragma unroll
    for(int j=0;j<3;j++){
      int lt = lt0-3+j;
      float v=0.f;
      if(lt>=0){ int lg = g ? (LTOK-1-lt) : lt; v=b2f(xz[((size_t)b*LTOK+lg)*128 + lane]); }
      xr[j]=v;
    }
    x0=xr[0]; x1=xr[1]; x2=xr[2];
  }
  for(int i0=0;i0<CLEN;i0+=8){
    bf16 xv[8]; float4 dv[8]; short4v bb[8];
    #pragma unroll
    for(int k=0;k<8;k++){
      int lt = lt0+i0+k;
      int lg = g ? (LTOK-1-lt) : lt;
      xv[k] = xz[((size_t)b*LTOK+lg)*128 + lane];
      size_t l = (size_t)gb*LTOK + lt;
      dv[k] = *(const float4*)(dtr + l*4);
      bb[k] = *(const short4v*)(bcg + l*16 + nh*4);
    }
    #pragma unroll
    for(int k=0;k<8;k++){
      float x3 = b2f(xv[k]);
      float pre = cb_ + cw0*x0 + cw1*x1 + cw2*x2 + cw3*x3;
      float xc = fsilu(pre);
      float v = db_ + dv[k].x*dw0 + dv[k].y*dw1 + dv[k].z*dw2 + dv[k].w*dw3;
      float e = fexp2(-LOG2E*fabsf(v));
      float dt = fmaxf(v,0.f) + __logf(1.f+e);
      Tsum += dt;
      float bx = dt*xc;
      float a[4];
      if(fastA){
        float e1 = fexp2(dt*acb2);
        if(nh==0){ a[0]=e1; a[1]=e1*e1; a[2]=a[1]*e1; a[3]=a[1]*a[1]; }
        else { float e2=e1*e1, e4=e2*e2; a[0]=e4*e1; a[1]=e4*e2; a[2]=a[1]*e1; a[3]=e4*e4; }
      }else{
        #pragma unroll
        for(int n=0;n<4;n++) a[n] = fexp2(dt*ac2[n]);
      }
      #pragma unroll
      for(int n=0;n<4;n++) S[n] = a[n]*S[n] + bx*s2f(bb[k][n]);
      x0=x1; x1=x2; x2=x3;
    }
  }
  int seq = (gb*64 + lane)*8 + nh*4;
  #pragma unroll
  for(int n=0;n<4;n++){
    psP[(size_t)chunk*NSEQ + seq + n] = fexp2(ac2[n]*Tsum);
    psS[(size_t)chunk*NSEQ + seq + n] = S[n];
  }
}

// ---------------------------------------------------------------- scan pass2: hierarchical (depth 1024 -> 32/32/32)
__global__ void k_scan2a(const float* __restrict__ psP, const float* __restrict__ psS,
                         float* __restrict__ segP, float* __restrict__ segS){
  int idx = blockIdx.x*256 + threadIdx.x;       // 65536 = NSEQ*SEG
  int seq = idx & (NSEQ-1);
  int seg = idx >> 11;
  float P = 1.f, S = 0.f;
  int i0 = seg*SEGLEN;
  #pragma unroll 4
  for(int i=0;i<SEGLEN;i++){
    float p = psP[(size_t)(i0+i)*NSEQ + seq];
    float s = psS[(size_t)(i0+i)*NSEQ + seq];
    S = p*S + s;
    P *= p;
  }
  segP[seg*NSEQ + seq] = P;
  segS[seg*NSEQ + seq] = S;
}
__global__ void k_scan2b(const float* __restrict__ segP, const float* __restrict__ segS,
                         float* __restrict__ segC){
  int seq = blockIdx.x*256 + threadIdx.x;
  if(seq >= NSEQ) return;
  float h = 0.f;
  #pragma unroll
  for(int s=0;s<SEG;s++){
    segC[s*NSEQ + seq] = h;
    h = segP[s*NSEQ + seq]*h + segS[s*NSEQ + seq];
  }
}
__global__ void k_scan2c(const float* __restrict__ psP, const float* __restrict__ segC,
                         float* __restrict__ psC){
  int idx = blockIdx.x*256 + threadIdx.x;
  int seq = idx & (NSEQ-1);
  int seg = idx >> 11;
  float h = segC[seg*NSEQ + seq];
  int i0 = seg*SEGLEN;
  #pragma unroll 4
  for(int i=0;i<SEGLEN;i++){
    float p = psP[(size_t)(i0+i)*NSEQ + seq];
    float s = psC[(size_t)(i0+i)*NSEQ + seq];   // read partial BEFORE overwrite
    psC[(size_t)(i0+i)*NSEQ + seq] = h;
    h = p*h + s;
  }
}

// ---------------------------------------------------------------- scan pass3: 2-wave n-split, LDS y-combine, exp-chain fast path (R18)
__global__ __launch_bounds__(128, 4) void k_scan3(
                        const bf16* __restrict__ xz, const float* __restrict__ dtr,
                        const bf16* __restrict__ bcg,
                        const void* __restrict__ c1w, const void* __restrict__ c1b,
                        const void* __restrict__ dpw, const void* __restrict__ dpb,
                        const void* __restrict__ alog, const void* __restrict__ ablog,
                        const void* __restrict__ dskip, const float* __restrict__ carry,
                        bf16* __restrict__ ybuf, const int* __restrict__ flag){
  const int f32 = *flag;
  __shared__ float ysh[2][8][64];    // 4 KB double buffer
  int bid = blockIdx.x;              // 4096
  int lane = threadIdx.x & 63;
  int nh   = threadIdx.x >> 6;
  int chunk = bid & (NC-1);
  int b = (bid>>10)&1;
  int g = bid>>11;
  int gb = g*2+b;
  const void* al = g ? ablog : alog;
  float ac2[4];
  #pragma unroll
  for(int n=0;n<4;n++) ac2[n] = -LOG2E*__expf(ldin(al, lane*8 + nh*4 + n, f32));
  float m0 = (float)(nh*4+1);
  float acb2 = ac2[0] / m0;
  bool okl = true;
  #pragma unroll
  for(int n=1;n<4;n++) okl = okl && (fabsf(ac2[n] - acb2*(m0+n)) <= 0.01f*fabsf(ac2[n]));
  const bool fastA = __all(okl);
  float cw0=ldin(c1w,lane*4+0,f32), cw1=ldin(c1w,lane*4+1,f32), cw2=ldin(c1w,lane*4+2,f32), cw3=ldin(c1w,lane*4+3,f32);
  float cb_=ldin(c1b,lane,f32);
  float dw0=ldin(dpw,lane*4+0,f32), dw1=ldin(dpw,lane*4+1,f32), dw2=ldin(dpw,lane*4+2,f32), dw3=ldin(dpw,lane*4+3,f32);
  float db_=ldin(dpb,lane,f32);
  float dsk = ldin(dskip,lane,f32);
  int seq = (gb*64 + lane)*8 + nh*4;
  float h[4];
  #pragma unroll
  for(int n=0;n<4;n++) h[n] = carry[(size_t)chunk*NSEQ + seq + n];
  int lt0 = chunk*CLEN;
  float x0,x1,x2;
  {
    float xr[3];
    #pragma unroll
    for(int j=0;j<3;j++){
      int lt = lt0-3+j;
      float v=0.f;
      if(lt>=0){ int lg = g ? (LTOK-1-lt) : lt; v=b2f(xz[((size_t)b*LTOK+lg)*128 + lane]); }
      xr[j]=v;
    }
    x0=xr[0]; x1=xr[1]; x2=xr[2];
  }
  for(int i0=0;i0<CLEN;i0+=8){
    int bt = (i0>>3)&1;
    bf16 xv[8]; float4 dv[8]; short4v bb[8], cc[8];
    #pragma unroll
    for(int k=0;k<8;k++){
      int lt = lt0+i0+k;
      int lg = g ? (LTOK-1-lt) : lt;
      xv[k] = xz[((size_t)b*LTOK+lg)*128 + lane];
      size_t l = (size_t)gb*LTOK + lt;
      dv[k] = *(const float4*)(dtr + l*4);
      bb[k] = *(const short4v*)(bcg + l*16 + nh*4);
      cc[k] = *(const short4v*)(bcg + l*16 + 8 + nh*4);
    }
    float py[8];
    #pragma unroll
    for(int k=0;k<8;k++){
      float x3 = b2f(xv[k]);
      float pre = cb_ + cw0*x0 + cw1*x1 + cw2*x2 + cw3*x3;
      float xc = fsilu(pre);
      float v = db_ + dv[k].x*dw0 + dv[k].y*dw1 + dv[k].z*dw2 + dv[k].w*dw3;
      float e = fexp2(-LOG2E*fabsf(v));
      float dt = fmaxf(v,0.f) + __logf(1.f+e);
      float bx = dt*xc;
      float part = nh ? xc*dsk : 0.f;
      float a[4];
      if(fastA){
        float e1 = fexp2(dt*acb2);
        if(nh==0){ a[0]=e1; a[1]=e1*e1; a[2]=a[1]*e1; a[3]=a[1]*a[1]; }
        else { float e2=e1*e1, e4=e2*e2; a[0]=e4*e1; a[1]=e4*e2; a[2]=a[1]*e1; a[3]=e4*e4; }
      }else{
        #pragma unroll
        for(int n=0;n<4;n++) a[n] = fexp2(dt*ac2[n]);
      }
      #pragma unroll
      for(int n=0;n<4;n++){
        h[n] = a[n]*h[n] + bx*s2f(bb[k][n]);
        part += h[n]*s2f(cc[k][n]);
      }
      if(nh==0) ysh[bt][k][lane] = part;
      else      py[k] = part;
      x0=x1; x1=x2; x2=x3;
    }
    __syncthreads();
    if(nh==1){
      #pragma unroll
      for(int k=0;k<8;k++){
        size_t l = (size_t)gb*LTOK + lt0+i0+k;
        ybuf[l*64 + lane] = f2b(ysh[bt][k][lane] + py[k]);
      }
    }
  }
}

// ---------------------------------------------------------------- combine dirs * silu(z) + out_proj (MFMA) + LN -> vol (token-major)
__global__ __launch_bounds__(256) void k_outln(
                        const bf16* __restrict__ ybuf, const bf16* __restrict__ xz,
                        const void* __restrict__ opw,
                        const void* __restrict__ lng, const void* __restrict__ lnb,
                        bf16* __restrict__ vol_t, const int* __restrict__ flag){
  const int f32 = *flag;
  __shared__ bf16 vsm[64*72];   // [token][d] pitch 72; reused for LN output staging
  __shared__ bf16 wsm[64*72];   // [c][d]     pitch 72
  __shared__ float gsm[64], bsm[64];
  int tid = threadIdx.x;
  int b = blockIdx.x >> 9, tile = blockIdx.x & 511;
  int l0 = tile*64;

  for(int p=tid; p<512; p+=256){           // weights (c, d8)
    int c = p & 63, d8 = p >> 6;
    short8 v;
    #pragma unroll
    for(int k=0;k<8;k++){ bf16 t = f2b(ldin(opw, c*64 + d8*8 + k, f32)); v[k] = *(short*)&t; }
    *(short8*)(&wsm[c*72 + d8*8]) = v;
  }
  if(tid<64){ gsm[tid]=ldin(lng,tid,f32); bsm[tid]=ldin(lnb,tid,f32); }
  for(int p=tid; p<4096; p+=256){          // v = 0.5(yf+yb)*silu(z)
    int tl = p >> 6, d = p & 63;
    int l = l0 + tl;
    float yf = b2f(ybuf[((size_t)(0+b)*LTOK + l)*64 + d]);
    float yb = b2f(ybuf[((size_t)(2+b)*LTOK + (LTOK-1-l))*64 + d]);
    float z  = b2f(xz[((size_t)b*LTOK + l)*128 + 64 + d]);
    vsm[tl*72 + d] = f2b(0.5f*(yf+yb)*fsilu(z));
  }
  __syncthreads();

  int lane = tid & 63, wv = tid >> 6, pn = lane & 15, quad = lane >> 4, kg8 = quad*8;
  f32x4 acc[4];
  #pragma unroll
  for(int nt=0;nt<4;nt++) acc[nt]=(f32x4)(0.f);
  #pragma unroll
  for(int kq=0;kq<2;kq++){
    short8 a = *(const short8*)(&vsm[(wv*16+pn)*72 + kq*32 + kg8]);
    #pragma unroll
    for(int nt=0;nt<4;nt++){
      short8 bb = *(const short8*)(&wsm[(nt*16+pn)*72 + kq*32 + kg8]);
      acc[nt] = __builtin_amdgcn_mfma_f32_16x16x32_bf16(a,bb,acc[nt],0,0,0);
    }
  }
  __syncthreads();   // all reads of vsm done; safe to overwrite below

  float gl[4], bl[4];
  #pragma unroll
  for(int nt=0;nt<4;nt++){ gl[nt]=gsm[nt*16+pn]; bl[nt]=bsm[nt*16+pn]; }
  #pragma unroll
  for(int r=0;r<4;r++){
    float vals[4]; float s=0.f;
    #pragma unroll
    for(int nt=0;nt<4;nt++){ vals[nt]=acc[nt][r]; s+=vals[nt]; }
    #pragma unroll
    for(int m=1;m<16;m<<=1) s += __shfl_xor(s, m);
    float mu = s*(1.f/64.f);
    float s2=0.f;
    #pragma unroll
    for(int nt=0;nt<4;nt++){ float dv=vals[nt]-mu; s2+=dv*dv; }
    #pragma unroll
    for(int m=1;m<16;m<<=1) s2 += __shfl_xor(s2, m);
    float inv = rsqrtf(s2*(1.f/64.f) + 1e-5f);
    int token = wv*16 + quad*4 + r;
    #pragma unroll
    for(int nt=0;nt<4;nt++){
      vsm[token*72 + nt*16 + pn] = f2b((vals[nt]-mu)*inv*gl[nt] + bl[nt]);
    }
  }
  __syncthreads();
  for(int p=tid; p<512; p+=256){           // coalesced token-major short8 stores
    int tl = p >> 3, d8 = p & 7;
    *(short8*)(&vol_t[((size_t)b*SP + l0 + tl)*64 + d8*8]) = *(const short8*)(&vsm[tl*72 + d8*8]);
  }
}

// ---------------------------------------------------------------- launch
extern "C" void kernel_launch(void* const* d_in, const int* in_sizes, int n_in,
                              void* d_out, int out_size, void* d_ws, size_t ws_size,
                              hipStream_t stream){
  const void* input  = d_in[0];
  const void* conv_w = d_in[1];
  const void* conv_b = d_in[2];
  const void* inpw   = d_in[3];
  const void* c1w    = d_in[4];
  const void* c1b    = d_in[5];
  const void* xpw    = d_in[6];
  const void* dpw    = d_in[7];
  const void* dpb    = d_in[8];
  const void* alog   = d_in[9];
  const void* ablog  = d_in[10];
  const void* dskip  = d_in[11];
  const void* opw    = d_in[12];
  const void* lng    = d_in[13];
  const void* lnb    = d_in[14];

  // R14 layout (NC=1024): psP/psS 8.4 MB; aliasing keeps NEED < 58 MB.
  //   ybuf (16.8M) aliases psP(8.4M)+xin_t(8.4M)  [both dead before scan3 writes ybuf]
  //   vol_t (8.4M) aliases psS                    [carry dead after scan3]
  char* base = (char*)d_ws;
  bf16*  skipb = (bf16*) (base + 0);            //  8,388,608 B
  bf16*  xz    = (bf16*) (base + 8388608);      // 16,777,216 B -> 25,165,824
  bf16*  bcg   = (bf16*) (base + 25165824);     //  4,194,304 B -> 29,360,128
  float* dtr   = (float*)(base + 29360128);     //  2,097,152 B -> 31,457,280
  float* psP   = (float*)(base + 31457280);     //  8,388,608 B -> 39,845,888 (NC*NSEQ*4)
  bf16*  xin_t = (bf16*) (base + 39845888);     //  8,388,608 B -> 48,234,496 (alias ybuf-hi)
  bf16*  ybuf  = (bf16*) (base + 31457280);     // 16,777,216 B alias psP+xin_t
  float* psS   = (float*)(base + 48234496);     //  8,388,608 B -> 56,623,104 (carry; vol_t alias)
  bf16*  vol_t = (bf16*) (base + 48234496);     //  8,388,608 B alias psS
  bf16*  wt    = (bf16*) (base + 56623104);     //    221,184 B -> 56,844,288
  float* segP  = (float*)(base + 56844288);     //    262,144 B -> 57,106,432
  float* segS  = (float*)(base + 57106432);     //    262,144 B -> 57,368,576
  float* segC  = (float*)(base + 57368576);     //    262,144 B -> 57,630,720
  int*   flagp = (int*)  (base + 57630720);     //  16 B -> 57,630,736
  float* zbuf  = (float*)(base + 57630736);     //  128 B zeros (convm halo source)
  const size_t NEED = 57630864;

  k_detect<<<dim3(1), dim3(64), 0, stream>>>(conv_w, flagp);

  if(ws_size < NEED){
    k_fill<<<dim3((out_size+255)/256), dim3(256), 0, stream>>>(d_out, out_size, flagp);
    return;
  }

  k_wprep  <<<dim3(432),   dim3(256), 0, stream>>>(conv_w, wt, zbuf, flagp);
  k_inprojm<<<dim3(512),   dim3(256), 0, stream>>>(input, inpw, xz, xin_t, flagp);
  // conv #1: xin_t -> skipb (bf16, channel-major out)
  k_convm  <<<dim3(1024),  dim3(256), 0, stream>>>(xin_t, wt, conv_b, nullptr, skipb, nullptr, 0, flagp, zbuf);
  k_inorm  <<<dim3(128),   dim3(256), 0, stream>>>(skipb);
  k_dirprep<<<dim3(2048),  dim3(256), 0, stream>>>(xz, c1w, c1b, xpw, bcg, dtr, flagp);
  k_scan1  <<<dim3(4096),  dim3(128), 0, stream>>>(xz, dtr, bcg, c1w, c1b, dpw, dpb, alog, ablog, psP, psS, flagp);
  k_scan2a <<<dim3(256),   dim3(256), 0, stream>>>(psP, psS, segP, segS);
  k_scan2b <<<dim3(8),     dim3(256), 0, stream>>>(segP, segS, segC);
  k_scan2c <<<dim3(256),   dim3(256), 0, stream>>>(psP, segC, psS);
  k_scan3  <<<dim3(4096),  dim3(128), 0, stream>>>(xz, dtr, bcg, c1w, c1b, dpw, dpb, alog, ablog, dskip, psS, ybuf, flagp);
  k_outln  <<<dim3(1024),  dim3(256), 0, stream>>>(ybuf, xz, opw, lng, lnb, vol_t, flagp);
  // conv #2: vol_t (+skipb) -> d_out, dual-dtype out
  k_convm  <<<dim3(1024),  dim3(256), 0, stream>>>(vol_t, wt, conv_b, skipb, nullptr, d_out, 1, flagp, zbuf);
}

// Round 16
// 381.768 us; speedup vs baseline: 1.1769x; 1.0308x over previous
//
#include <hip/hip_runtime.h>
#include <hip/hip_bf16.h>

typedef __hip_bfloat16 bf16;
typedef __attribute__((ext_vector_type(8))) short short8;   // 8 bf16 = 4 VGPRs
typedef __attribute__((ext_vector_type(4))) short short4v;  // 4 bf16 = 2 VGPRs
typedef __attribute__((ext_vector_type(4))) float f32x4;    // MFMA acc

__device__ __forceinline__ float b2f(bf16 x){ return __bfloat162float(x); }
__device__ __forceinline__ bf16  f2b(float x){ return __float2bfloat16(x); }
__device__ __forceinline__ float s2f(short s){ bf16 t = *(bf16*)&s; return b2f(t); }

#define LOG2E 1.4426950408889634f

// raw v_exp_f32 (computes 2^x)
__device__ __forceinline__ float fexp2(float x){ return __builtin_amdgcn_exp2f(x); }

// fast silu: x * rcp(1+e^-x)  (v_rcp_f32, ~1ulp -- fine at bf16 output precision)
__device__ __forceinline__ float fsilu(float x){
  return x * __builtin_amdgcn_rcpf(1.f + fexp2(-LOG2E*x));
}

// dual-dtype input load / output store (flag: 1 = fp32 storage, 0 = bf16)
__device__ __forceinline__ float ldin(const void* p, size_t i, int f32){
  return f32 ? ((const float*)p)[i] : b2f(((const bf16*)p)[i]);
}
__device__ __forceinline__ void stout(void* p, size_t i, float v, int f32){
  if(f32) ((float*)p)[i] = v; else ((bf16*)p)[i] = f2b(v);
}

constexpr int SP   = 32*32*32;   // 32768 spatial per (b,c)
constexpr int LTOK = SP;         // tokens per batch
constexpr int NC   = 1024;       // scan chunks
constexpr int CLEN = LTOK / NC;  // 32
constexpr int NSEQ = 2*2*64*8;   // 2048 scan sequences (dir,b,d,n)
constexpr int SEG  = 32;         // scan2 hierarchy: 32 segments x 32 chunks
constexpr int SEGLEN = NC/SEG;   // 32

// ---------------------------------------------------------------- dtype detector
__global__ void k_detect(const void* conv_w, int* flag){
  if(threadIdx.x==0 && blockIdx.x==0){
    const bf16* p = (const bf16*)conv_w;
    int f = 0;
    for(int i=0;i<128;i++){
      float v = b2f(p[i]);
      if(!(v==v) || fabsf(v) > 1.0f) f = 1;   // bf16 weights are 0.05-scale
    }
    *flag = f;
  }
}

// ---------------------------------------------------------------- diagnostic fill
__global__ void k_fill(void* out, int n, const int* flag){
  const int f32 = *flag;
  int i = blockIdx.x*256 + threadIdx.x;
  if(i<n) stout(out, i, 12345.0f, f32);
}

// ---------------------------------------------------------------- weight re-layout: wt[tap][oc][ci] (+ zero the halo source buffer)
__global__ void k_wprep(const void* __restrict__ cw, bf16* __restrict__ wt,
                        float* __restrict__ zbuf, const int* __restrict__ flag){
  const int f32 = *flag;
  if(blockIdx.x==0 && threadIdx.x<32) zbuf[threadIdx.x] = 0.f;   // 128B zeros for convm halo
  int t = blockIdx.x*256 + threadIdx.x;   // 110592 = 27*64*64
  if(t >= 27*64*64) return;
  int tap = t >> 12;          // /4096
  int oc  = (t >> 6) & 63;
  int ci  = t & 63;
  wt[t] = f2b(ldin(cw, ((size_t)(oc*64+ci))*27 + tap, f32));
}

// ---------------------------------------------------------------- in_proj as MFMA GEMM
__global__ __launch_bounds__(256) void k_inprojm(
    const void* __restrict__ in, const void* __restrict__ pw,
    bf16* __restrict__ xz, bf16* __restrict__ xin_t,
    const int* __restrict__ flag){
  const int f32 = *flag;
  __shared__ bf16 tok[128*72];   // [token][c], pitch 72
  __shared__ bf16 wl [128*72];   // [j][c],     pitch 72
  int tid = threadIdx.x;
  int b = blockIdx.x >> 8, tile = blockIdx.x & 255;
  int l0 = tile*128;

  for(int p=tid; p<1024; p+=256){          // weights: (j, c8)
    int j = p & 127, c8 = p >> 7;
    short8 v;
    #pragma unroll
    for(int k=0;k<8;k++){
      bf16 t = f2b(ldin(pw, j*64 + c8*8 + k, f32));
      v[k] = *(short*)&t;
    }
    *(short8*)(&wl[j*72 + c8*8]) = v;
  }
  for(int p=tid; p<1024; p+=256){          // tokens: (i, c8), coalesced over i
    int i = p & 127, c8 = p >> 7;
    short8 v;
    #pragma unroll
    for(int k=0;k<8;k++){
      bf16 t = f2b(ldin(in, ((size_t)(b*64 + c8*8 + k))*SP + l0 + i, f32));
      v[k] = *(short*)&t;
    }
    *(short8*)(&tok[i*72 + c8*8]) = v;
  }
  __syncthreads();

  int lane = tid & 63, wv = tid >> 6;
  int pn = lane & 15, quad = lane >> 4, kg8 = quad*8;
  f32x4 acc[2][8];
  #pragma unroll
  for(int mt=0;mt<2;mt++)
    #pragma unroll
    for(int nt=0;nt<8;nt++) acc[mt][nt]=(f32x4)(0.f);

  #pragma unroll
  for(int kq=0;kq<2;kq++){
    short8 a0 = *(const short8*)(&tok[(wv*32      + pn)*72 + kq*32 + kg8]);
    short8 a1 = *(const short8*)(&tok[(wv*32 + 16 + pn)*72 + kq*32 + kg8]);
    #pragma unroll
    for(int nt=0;nt<8;nt++){
      short8 bb = *(const short8*)(&wl[(nt*16+pn)*72 + kq*32 + kg8]);
      acc[0][nt] = __builtin_amdgcn_mfma_f32_16x16x32_bf16(a0,bb,acc[0][nt],0,0,0);
      acc[1][nt] = __builtin_amdgcn_mfma_f32_16x16x32_bf16(a1,bb,acc[1][nt],0,0,0);
    }
  }

  #pragma unroll
  for(int mt=0;mt<2;mt++){
    #pragma unroll
    for(int nt=0;nt<8;nt++){
      #pragma unroll
      for(int r=0;r<4;r++){
        int token = wv*32 + mt*16 + quad*4 + r;
        xz[((size_t)b*LTOK + l0 + token)*128 + nt*16 + pn] = f2b(acc[mt][nt][r]);
      }
    }
  }
  for(int p=tid; p<8192; p+=256){
    int i = p >> 6, c = p & 63;
    xin_t[((size_t)b*SP + l0 + i)*64 + c] = tok[i*72 + c];
  }
}

// ---------------------------------------------------------------- MFMA conv3d (both convs)
// R23 = R20 (proven 53.6-60.8us steady): staging via global_load_lds (width 16).
// LDS: linear 16B units, pitch 32 (64B rows), XOR-quad bank swizzle.
// Halo lanes source a zero buffer. 64KB LDS, 2 blocks/CU, d-half tile.
// R24: mode==1 fuses instance-norm+relu into the skip read (statb = per-(b,c)
// {mean, rsqrt(var+eps)}), eliminating k_inorm's 16.8MB normalize pass.
// Ledger (frozen): DMA WIN, swizzle WIN, 32-oc neutral, d-quarter/w-split/8-wave
// all regress (traffic explosion or occupancy no-show). Structure local-optimal.
__global__ __launch_bounds__(256, 2) void k_convm(
    const bf16* __restrict__ xin_t, const bf16* __restrict__ wt,
    const void* __restrict__ cb, const bf16* __restrict__ skip,
    const float* __restrict__ statb,
    bf16* __restrict__ out_bf, void* __restrict__ out_any,
    int mode, const int* __restrict__ flag, const float* __restrict__ zbuf){
  const int f32 = *flag;
  __shared__ bf16 xt[4096*8];  // 4096 16B-units = 65,536 B (972*4=3888 used + pad)

  int tid  = threadIdx.x;
  int lane = tid & 63;
  int wv   = tid >> 6;
  int pn   = lane & 15;
  int quad = lane >> 4;
  int kg8  = quad * 8;
  int laneA = pn*64 + kg8;

  int blk0 = blockIdx.x;                       // 1024 blocks
  int blk  = (blk0 & 7)*128 + (blk0 >> 3);     // bijective XCD-contiguous remap
  int ocg = blk & 3;
  int wh  = (blk >> 2) & 1;
  int dh2 = (blk >> 3) & 1;
  int h   = (blk >> 4) & 31;
  int b   = blk >> 9;
  int w0  = wh*16;
  int d0  = dh2*16;

  f32x4 acc[4];                 // [wr]
  #pragma unroll
  for(int m=0;m<4;m++) acc[m]=(f32x4)(0.f);

  for(int cic=0; cic<64; cic+=32){
    if(cic) __syncthreads();
    // stage 3h x 18w x 18d x 32ci via LDS-DMA; every unit (incl. pad) written
    {
      bf16* dstw = &xt[(size_t)(wv*64)*8];     // wave-uniform base, lane x 16B implicit
      for(int it=0; it<16; it++){
        int u = it*256 + tid;                  // physical 16B unit (linear)
        int row = u >> 2;
        int q4  = (u & 3) ^ ((u >> 3) & 3);    // inverse swizzle -> logical ci-quad
        int hh = row / 324; int rem = row - hh*324;
        int ww = rem / 18;  int dd = rem - ww*18;
        int hg = h + hh - 1, wg = w0 + ww - 1, d = d0 + dd - 1;
        bool ok = ((unsigned)hg < 32u) && ((unsigned)wg < 32u) && ((unsigned)d < 32u);
        const void* src = ok
          ? (const void*)&xin_t[(((size_t)b*SP) + hg*1024 + wg*32 + d)*64 + cic + q4*8]
          : (const void*)zbuf;
        __builtin_amdgcn_global_load_lds(
            (const __attribute__((address_space(1))) void*)src,
            (__attribute__((address_space(3))) void*)(dstw + (size_t)it*256*8),
            16, 0, 0);
      }
    }
    __syncthreads();

    // hoist all 27 taps' A-frags for this ocg+chunk into registers
    short8 afr[27];
    #pragma unroll
    for(int t=0;t<27;t++)
      afr[t] = *(const short8*)(wt + t*4096 + ocg*1024 + cic + laneA);

    #pragma unroll
    for(int kz=0;kz<3;kz++){
      #pragma unroll
      for(int ky=0;ky<3;ky++){
        #pragma unroll
        for(int kx=0;kx<3;kx++){
          int tap = (kz*3+ky)*3+kx;
          #pragma unroll
          for(int wr=0;wr<4;wr++){
            int rix = (kz*18 + wv*4 + wr + ky)*18 + kx + pn;
            int punit = rix*4 + (quad ^ ((rix>>1)&3));   // swizzled read
            short8 bb = *(const short8*)(&xt[(size_t)punit*8]);
            acc[wr] = __builtin_amdgcn_mfma_f32_16x16x32_bf16(afr[tap], bb, acc[wr], 0,0,0);
          }
        }
      }
    }
  }

  float mn[4], iv[4];
  if(mode==1){
    #pragma unroll
    for(int r=0;r<4;r++){
      int bc = b*64 + ocg*16 + quad*4 + r;
      mn[r] = statb[bc*2];
      iv[r] = statb[bc*2+1];
    }
  }
  #pragma unroll
  for(int wr=0;wr<4;wr++){
    #pragma unroll
    for(int r=0;r<4;r++){
      int oc = ocg*16 + quad*4 + r;
      size_t idx = ((size_t)(b*64+oc))*SP + h*1024 + (w0 + wv*4 + wr)*32 + d0 + pn;
      float v = acc[wr][r] + ldin(cb, oc, f32);
      if(mode==0) out_bf[idx] = f2b(v);
      else{
        float sk = (b2f(skip[idx]) - mn[r]) * iv[r];   // fused instance-norm
        stout(out_any, idx, v + (sk > 0.f ? sk : 0.f), f32);
      }
    }
  }
}

// ---------------------------------------------------------------- instance-norm stats only (R24): per-(b,c) mean + rsqrt(var+eps)
__global__ void k_instat(const bf16* __restrict__ buf, float* __restrict__ statb){
  int bc = blockIdx.x;
  const bf16* p = buf + (size_t)bc*SP;
  float s=0.f, s2=0.f;
  for(int i=threadIdx.x;i<SP;i+=256){ float v=b2f(p[i]); s+=v; s2+=v*v; }
  __shared__ float sh[8];
  #pragma unroll
  for(int m=32;m>=1;m>>=1){ s += __shfl_xor(s,m); s2 += __shfl_xor(s2,m); }
  int wid = threadIdx.x>>6;
  if((threadIdx.x&63)==0){ sh[wid]=s; sh[4+wid]=s2; }
  __syncthreads();
  if(threadIdx.x==0){
    float a=0,b2=0;
    for(int i=0;i<4;i++){a+=sh[i]; b2+=sh[4+i];}
    float mean = a*(1.f/SP);
    float var  = b2*(1.f/SP) - mean*mean;
    statb[bc*2]   = mean;
    statb[bc*2+1] = rsqrtf(fmaxf(var,0.f) + 1e-5f);
  }
}

// ---------------------------------------------------------------- per-direction prep: conv1d+silu, x_proj
// R14 structure; R18: rcp-silu.
__global__ __launch_bounds__(256) void k_dirprep(
                          const bf16* __restrict__ xz, const void* __restrict__ c1w,
                          const void* __restrict__ c1b, const void* __restrict__ xpw,
                          bf16* __restrict__ bcg, float* __restrict__ dtr,
                          const int* __restrict__ flag){
  const int f32 = *flag;
  __shared__ float xs[67][64];
  __shared__ float xcs[64][68];   // pitch 68 floats: 16B-aligned rows
  __shared__ float xws[20][68];
  int bid = blockIdx.x;
  int g = bid >> 10, b = (bid>>9)&1, tile = bid & 511;
  int l0 = tile*64;
  int gb = g*2+b;
  int tid = threadIdx.x;
  for(int t=tid; t<20*64; t+=256){ int j=t>>6, d=t&63; xws[j][d]=ldin(xpw, t, f32); }
  for(int t=tid; t<67*64; t+=256){
    int row=t>>6, d=t&63;
    int l = l0 + row - 3;
    float v = 0.f;
    if(l>=0 && l<LTOK){
      int lg = g ? (LTOK-1-l) : l;
      v = b2f(xz[((size_t)b*LTOK + lg)*128 + d]);
    }
    xs[row][d]=v;
  }
  __syncthreads();
  {
    int d = tid & 63;
    float cw0=ldin(c1w,d*4+0,f32), cw1=ldin(c1w,d*4+1,f32),
          cw2=ldin(c1w,d*4+2,f32), cw3=ldin(c1w,d*4+3,f32);
    float cb_=ldin(c1b,d,f32);
    for(int tl = tid>>6; tl<64; tl+=4){
      float acc = cb_ + cw0*xs[tl][d] + cw1*xs[tl+1][d] + cw2*xs[tl+2][d] + cw3*xs[tl+3][d];
      xcs[tl][d] = fsilu(acc);
    }
  }
  __syncthreads();
  {
    int tl = tid & 63, wq = tid >> 6;      // wave wq owns j = wq*5 .. wq*5+4
    float acc[5] = {0.f,0.f,0.f,0.f,0.f};
    #pragma unroll 4
    for(int d4=0; d4<16; d4++){
      float4 xv = *(const float4*)(&xcs[tl][d4*4]);
      #pragma unroll
      for(int jj=0; jj<5; jj++){
        float4 wv = *(const float4*)(&xws[wq*5+jj][d4*4]);   // wave-broadcast
        acc[jj] += xv.x*wv.x + xv.y*wv.y + xv.z*wv.z + xv.w*wv.w;
      }
    }
    size_t l = (size_t)gb*LTOK + l0 + tl;
    #pragma unroll
    for(int jj=0; jj<5; jj++){
      int j = wq*5 + jj;
      if(j<4) dtr[l*4 + j] = acc[jj];
      else    bcg[l*16 + (j-4)] = f2b(acc[jj]);
    }
  }
}

// ---------------------------------------------------------------- scan pass1: 2-wave n-split, exp-chain fast path (R18)
__global__ __launch_bounds__(128, 4) void k_scan1(
                        const bf16* __restrict__ xz, const float* __restrict__ dtr,
                        const bf16* __restrict__ bcg,
                        const void* __restrict__ c1w, const void* __restrict__ c1b,
                        const void* __restrict__ dpw, const void* __restrict__ dpb,
                        const void* __restrict__ alog, const void* __restrict__ ablog,
                        float* __restrict__ psP, float* __restrict__ psS,
                        const int* __restrict__ flag){
  const int f32 = *flag;
  int bid = blockIdx.x;              // 4096 = 2g * 2b * NC
  int lane = threadIdx.x & 63;
  int nh   = threadIdx.x >> 6;       // n-half (0 or 1)
  int chunk = bid & (NC-1);
  int b = (bid>>10)&1;
  int g = bid>>11;
  int gb = g*2+b;
  const void* al = g ? ablog : alog;
  float ac2[4];                      // exp2-ready: ac * log2(e)
  #pragma unroll
  for(int n=0;n<4;n++) ac2[n] = -LOG2E*__expf(ldin(al, lane*8 + nh*4 + n, f32));
  // A-structure detection: ac[n] ~ acb * (nh*4+n+1)  (exact for this model's A_log)
  float m0 = (float)(nh*4+1);
  float acb2 = ac2[0] / m0;
  bool okl = true;
  #pragma unroll
  for(int n=1;n<4;n++) okl = okl && (fabsf(ac2[n] - acb2*(m0+n)) <= 0.01f*fabsf(ac2[n]));
  const bool fastA = __all(okl);
  float cw0=ldin(c1w,lane*4+0,f32), cw1=ldin(c1w,lane*4+1,f32), cw2=ldin(c1w,lane*4+2,f32), cw3=ldin(c1w,lane*4+3,f32);
  float cb_=ldin(c1b,lane,f32);
  float dw0=ldin(dpw,lane*4+0,f32), dw1=ldin(dpw,lane*4+1,f32), dw2=ldin(dpw,lane*4+2,f32), dw3=ldin(dpw,lane*4+3,f32);
  float db_=ldin(dpb,lane,f32);
  float S[4];
  #pragma unroll
  for(int n=0;n<4;n++) S[n]=0.f;
  float Tsum = 0.f;
  int lt0 = chunk*CLEN;
  float x0,x1,x2;
  {
    float xr[3];
    #pragma unroll
    for(int j=0;j<3;j++){
      int lt = lt0-3+j;
      float v=0.f;
      if(lt>=0){ int lg = g ? (LTOK-1-lt) : lt; v=b2f(xz[((size_t)b*LTOK+lg)*128 + lane]); }
      xr[j]=v;
    }
    x0=xr[0]; x1=xr[1]; x2=xr[2];
  }
  for(int i0=0;i0<CLEN;i0+=8){
    bf16 xv[8]; float4 dv[8]; short4v bb[8];
    #pragma unroll
    for(int k=0;k<8;k++){
      int lt = lt0+i0+k;
      int lg = g ? (LTOK-1-lt) : lt;
      xv[k] = xz[((size_t)b*LTOK+lg)*128 + lane];
      size_t l = (size_t)gb*LTOK + lt;
      dv[k] = *(const float4*)(dtr + l*4);
      bb[k] = *(const short4v*)(bcg + l*16 + nh*4);
    }
    #pragma unroll
    for(int k=0;k<8;k++){
      float x3 = b2f(xv[k]);
      float pre = cb_ + cw0*x0 + cw1*x1 + cw2*x2 + cw3*x3;
      float xc = fsilu(pre);
      float v = db_ + dv[k].x*dw0 + dv[k].y*dw1 + dv[k].z*dw2 + dv[k].w*dw3;
      float e = fexp2(-LOG2E*fabsf(v));
      float dt = fmaxf(v,0.f) + __logf(1.f+e);
      Tsum += dt;
      float bx = dt*xc;
      float a[4];
      if(fastA){
        float e1 = fexp2(dt*acb2);
        if(nh==0){ a[0]=e1; a[1]=e1*e1; a[2]=a[1]*e1; a[3]=a[1]*a[1]; }
        else { float e2=e1*e1, e4=e2*e2; a[0]=e4*e1; a[1]=e4*e2; a[2]=a[1]*e1; a[3]=e4*e4; }
      }else{
        #pragma unroll
        for(int n=0;n<4;n++) a[n] = fexp2(dt*ac2[n]);
      }
      #pragma unroll
      for(int n=0;n<4;n++) S[n] = a[n]*S[n] + bx*s2f(bb[k][n]);
      x0=x1; x1=x2; x2=x3;
    }
  }
  int seq = (gb*64 + lane)*8 + nh*4;
  #pragma unroll
  for(int n=0;n<4;n++){
    psP[(size_t)chunk*NSEQ + seq + n] = fexp2(ac2[n]*Tsum);
    psS[(size_t)chunk*NSEQ + seq + n] = S[n];
  }
}

// ---------------------------------------------------------------- scan pass2: hierarchical (depth 1024 -> 32/32/32)
__global__ void k_scan2a(const float* __restrict__ psP, const float* __restrict__ psS,
                         float* __restrict__ segP, float* __restrict__ segS){
  int idx = blockIdx.x*256 + threadIdx.x;       // 65536 = NSEQ*SEG
  int seq = idx & (NSEQ-1);
  int seg = idx >> 11;
  float P = 1.f, S = 0.f;
  int i0 = seg*SEGLEN;
  #pragma unroll 4
  for(int i=0;i<SEGLEN;i++){
    float p = psP[(size_t)(i0+i)*NSEQ + seq];
    float s = psS[(size_t)(i0+i)*NSEQ + seq];
    S = p*S + s;
    P *= p;
  }
  segP[seg*NSEQ + seq] = P;
  segS[seg*NSEQ + seq] = S;
}
__global__ void k_scan2b(const float* __restrict__ segP, const float* __restrict__ segS,
                         float* __restrict__ segC){
  int seq = blockIdx.x*256 + threadIdx.x;
  if(seq >= NSEQ) return;
  float h = 0.f;
  #pragma unroll
  for(int s=0;s<SEG;s++){
    segC[s*NSEQ + seq] = h;
    h = segP[s*NSEQ + seq]*h + segS[s*NSEQ + seq];
  }
}
__global__ void k_scan2c(const float* __restrict__ psP, const float* __restrict__ segC,
                         float* __restrict__ psC){
  int idx = blockIdx.x*256 + threadIdx.x;
  int seq = idx & (NSEQ-1);
  int seg = idx >> 11;
  float h = segC[seg*NSEQ + seq];
  int i0 = seg*SEGLEN;
  #pragma unroll 4
  for(int i=0;i<SEGLEN;i++){
    float p = psP[(size_t)(i0+i)*NSEQ + seq];
    float s = psC[(size_t)(i0+i)*NSEQ + seq];   // read partial BEFORE overwrite
    psC[(size_t)(i0+i)*NSEQ + seq] = h;
    h = p*h + s;
  }
}

// ---------------------------------------------------------------- scan pass3: 2-wave n-split, LDS y-combine, exp-chain fast path (R18)
__global__ __launch_bounds__(128, 4) void k_scan3(
                        const bf16* __restrict__ xz, const float* __restrict__ dtr,
                        const bf16* __restrict__ bcg,
                        const void* __restrict__ c1w, const void* __restrict__ c1b,
                        const void* __restrict__ dpw, const void* __restrict__ dpb,
                        const void* __restrict__ alog, const void* __restrict__ ablog,
                        const void* __restrict__ dskip, const float* __restrict__ carry,
                        bf16* __restrict__ ybuf, const int* __restrict__ flag){
  const int f32 = *flag;
  __shared__ float ysh[2][8][64];    // 4 KB double buffer
  int bid = blockIdx.x;              // 4096
  int lane = threadIdx.x & 63;
  int nh   = threadIdx.x >> 6;
  int chunk = bid & (NC-1);
  int b = (bid>>10)&1;
  int g = bid>>11;
  int gb = g*2+b;
  const void* al = g ? ablog : alog;
  float ac2[4];
  #pragma unroll
  for(int n=0;n<4;n++) ac2[n] = -LOG2E*__expf(ldin(al, lane*8 + nh*4 + n, f32));
  float m0 = (float)(nh*4+1);
  float acb2 = ac2[0] / m0;
  bool okl = true;
  #pragma unroll
  for(int n=1;n<4;n++) okl = okl && (fabsf(ac2[n] - acb2*(m0+n)) <= 0.01f*fabsf(ac2[n]));
  const bool fastA = __all(okl);
  float cw0=ldin(c1w,lane*4+0,f32), cw1=ldin(c1w,lane*4+1,f32), cw2=ldin(c1w,lane*4+2,f32), cw3=ldin(c1w,lane*4+3,f32);
  float cb_=ldin(c1b,lane,f32);
  float dw0=ldin(dpw,lane*4+0,f32), dw1=ldin(dpw,lane*4+1,f32), dw2=ldin(dpw,lane*4+2,f32), dw3=ldin(dpw,lane*4+3,f32);
  float db_=ldin(dpb,lane,f32);
  float dsk = ldin(dskip,lane,f32);
  int seq = (gb*64 + lane)*8 + nh*4;
  float h[4];
  #pragma unroll
  for(int n=0;n<4;n++) h[n] = carry[(size_t)chunk*NSEQ + seq + n];
  int lt0 = chunk*CLEN;
  float x0,x1,x2;
  {
    float xr[3];
    #pragma unroll
    for(int j=0;j<3;j++){
      int lt = lt0-3+j;
      float v=0.f;
      if(lt>=0){ int lg = g ? (LTOK-1-lt) : lt; v=b2f(xz[((size_t)b*LTOK+lg)*128 + lane]); }
      xr[j]=v;
    }
    x0=xr[0]; x1=xr[1]; x2=xr[2];
  }
  for(int i0=0;i0<CLEN;i0+=8){
    int bt = (i0>>3)&1;
    bf16 xv[8]; float4 dv[8]; short4v bb[8], cc[8];
    #pragma unroll
    for(int k=0;k<8;k++){
      int lt = lt0+i0+k;
      int lg = g ? (LTOK-1-lt) : lt;
      xv[k] = xz[((size_t)b*LTOK+lg)*128 + lane];
      size_t l = (size_t)gb*LTOK + lt;
      dv[k] = *(const float4*)(dtr + l*4);
      bb[k] = *(const short4v*)(bcg + l*16 + nh*4);
      cc[k] = *(const short4v*)(bcg + l*16 + 8 + nh*4);
    }
    float py[8];
    #pragma unroll
    for(int k=0;k<8;k++){
      float x3 = b2f(xv[k]);
      float pre = cb_ + cw0*x0 + cw1*x1 + cw2*x2 + cw3*x3;
      float xc = fsilu(pre);
      float v = db_ + dv[k].x*dw0 + dv[k].y*dw1 + dv[k].z*dw2 + dv[k].w*dw3;
      float e = fexp2(-LOG2E*fabsf(v));
      float dt = fmaxf(v,0.f) + __logf(1.f+e);
      float bx = dt*xc;
      float part = nh ? xc*dsk : 0.f;
      float a[4];
      if(fastA){
        float e1 = fexp2(dt*acb2);
        if(nh==0){ a[0]=e1; a[1]=e1*e1; a[2]=a[1]*e1; a[3]=a[1]*a[1]; }
        else { float e2=e1*e1, e4=e2*e2; a[0]=e4*e1; a[1]=e4*e2; a[2]=a[1]*e1; a[3]=e4*e4; }
      }else{
        #pragma unroll
        for(int n=0;n<4;n++) a[n] = fexp2(dt*ac2[n]);
      }
      #pragma unroll
      for(int n=0;n<4;n++){
        h[n] = a[n]*h[n] + bx*s2f(bb[k][n]);
        part += h[n]*s2f(cc[k][n]);
      }
      if(nh==0) ysh[bt][k][lane] = part;
      else      py[k] = part;
      x0=x1; x1=x2; x2=x3;
    }
    __syncthreads();
    if(nh==1){
      #pragma unroll
      for(int k=0;k<8;k++){
        size_t l = (size_t)gb*LTOK + lt0+i0+k;
        ybuf[l*64 + lane] = f2b(ysh[bt][k][lane] + py[k]);
      }
    }
  }
}

// ---------------------------------------------------------------- combine dirs * silu(z) + out_proj (MFMA) + LN -> vol (token-major)
__global__ __launch_bounds__(256) void k_outln(
                        const bf16* __restrict__ ybuf, const bf16* __restrict__ xz,
                        const void* __restrict__ opw,
                        const void* __restrict__ lng, const void* __restrict__ lnb,
                        bf16* __restrict__ vol_t, const int* __restrict__ flag){
  const int f32 = *flag;
  __shared__ bf16 vsm[64*72];   // [token][d] pitch 72; reused for LN output staging
  __shared__ bf16 wsm[64*72];   // [c][d]     pitch 72
  __shared__ float gsm[64], bsm[64];
  int tid = threadIdx.x;
  int b = blockIdx.x >> 9, tile = blockIdx.x & 511;
  int l0 = tile*64;

  for(int p=tid; p<512; p+=256){           // weights (c, d8)
    int c = p & 63, d8 = p >> 6;
    short8 v;
    #pragma unroll
    for(int k=0;k<8;k++){ bf16 t = f2b(ldin(opw, c*64 + d8*8 + k, f32)); v[k] = *(short*)&t; }
    *(short8*)(&wsm[c*72 + d8*8]) = v;
  }
  if(tid<64){ gsm[tid]=ldin(lng,tid,f32); bsm[tid]=ldin(lnb,tid,f32); }
  for(int p=tid; p<4096; p+=256){          // v = 0.5(yf+yb)*silu(z)
    int tl = p >> 6, d = p & 63;
    int l = l0 + tl;
    float yf = b2f(ybuf[((size_t)(0+b)*LTOK + l)*64 + d]);
    float yb = b2f(ybuf[((size_t)(2+b)*LTOK + (LTOK-1-l))*64 + d]);
    float z  = b2f(xz[((size_t)b*LTOK + l)*128 + 64 + d]);
    vsm[tl*72 + d] = f2b(0.5f*(yf+yb)*fsilu(z));
  }
  __syncthreads();

  int lane = tid & 63, wv = tid >> 6, pn = lane & 15, quad = lane >> 4, kg8 = quad*8;
  f32x4 acc[4];
  #pragma unroll
  for(int nt=0;nt<4;nt++) acc[nt]=(f32x4)(0.f);
  #pragma unroll
  for(int kq=0;kq<2;kq++){
    short8 a = *(const short8*)(&vsm[(wv*16+pn)*72 + kq*32 + kg8]);
    #pragma unroll
    for(int nt=0;nt<4;nt++){
      short8 bb = *(const short8*)(&wsm[(nt*16+pn)*72 + kq*32 + kg8]);
      acc[nt] = __builtin_amdgcn_mfma_f32_16x16x32_bf16(a,bb,acc[nt],0,0,0);
    }
  }
  __syncthreads();   // all reads of vsm done; safe to overwrite below

  float gl[4], bl[4];
  #pragma unroll
  for(int nt=0;nt<4;nt++){ gl[nt]=gsm[nt*16+pn]; bl[nt]=bsm[nt*16+pn]; }
  #pragma unroll
  for(int r=0;r<4;r++){
    float vals[4]; float s=0.f;
    #pragma unroll
    for(int nt=0;nt<4;nt++){ vals[nt]=acc[nt][r]; s+=vals[nt]; }
    #pragma unroll
    for(int m=1;m<16;m<<=1) s += __shfl_xor(s, m);
    float mu = s*(1.f/64.f);
    float s2=0.f;
    #pragma unroll
    for(int nt=0;nt<4;nt++){ float dv=vals[nt]-mu; s2+=dv*dv; }
    #pragma unroll
    for(int m=1;m<16;m<<=1) s2 += __shfl_xor(s2, m);
    float inv = rsqrtf(s2*(1.f/64.f) + 1e-5f);
    int token = wv*16 + quad*4 + r;
    #pragma unroll
    for(int nt=0;nt<4;nt++){
      vsm[token*72 + nt*16 + pn] = f2b((vals[nt]-mu)*inv*gl[nt] + bl[nt]);
    }
  }
  __syncthreads();
  for(int p=tid; p<512; p+=256){           // coalesced token-major short8 stores
    int tl = p >> 3, d8 = p & 7;
    *(short8*)(&vol_t[((size_t)b*SP + l0 + tl)*64 + d8*8]) = *(const short8*)(&vsm[tl*72 + d8*8]);
  }
}

// ---------------------------------------------------------------- launch
extern "C" void kernel_launch(void* const* d_in, const int* in_sizes, int n_in,
                              void* d_out, int out_size, void* d_ws, size_t ws_size,
                              hipStream_t stream){
  const void* input  = d_in[0];
  const void* conv_w = d_in[1];
  const void* conv_b = d_in[2];
  const void* inpw   = d_in[3];
  const void* c1w    = d_in[4];
  const void* c1b    = d_in[5];
  const void* xpw    = d_in[6];
  const void* dpw    = d_in[7];
  const void* dpb    = d_in[8];
  const void* alog   = d_in[9];
  const void* ablog  = d_in[10];
  const void* dskip  = d_in[11];
  const void* opw    = d_in[12];
  const void* lng    = d_in[13];
  const void* lnb    = d_in[14];

  // R14 layout (NC=1024): psP/psS 8.4 MB; aliasing keeps NEED < 58 MB.
  //   ybuf (16.8M) aliases psP(8.4M)+xin_t(8.4M)  [both dead before scan3 writes ybuf]
  //   vol_t (8.4M) aliases psS                    [carry dead after scan3]
  char* base = (char*)d_ws;
  bf16*  skipb = (bf16*) (base + 0);            //  8,388,608 B
  bf16*  xz    = (bf16*) (base + 8388608);      // 16,777,216 B -> 25,165,824
  bf16*  bcg   = (bf16*) (base + 25165824);     //  4,194,304 B -> 29,360,128
  float* dtr   = (float*)(base + 29360128);     //  2,097,152 B -> 31,457,280
  float* psP   = (float*)(base + 31457280);     //  8,388,608 B -> 39,845,888 (NC*NSEQ*4)
  bf16*  xin_t = (bf16*) (base + 39845888);     //  8,388,608 B -> 48,234,496 (alias ybuf-hi)
  bf16*  ybuf  = (bf16*) (base + 31457280);     // 16,777,216 B alias psP+xin_t
  float* psS   = (float*)(base + 48234496);     //  8,388,608 B -> 56,623,104 (carry; vol_t alias)
  bf16*  vol_t = (bf16*) (base + 48234496);     //  8,388,608 B alias psS
  bf16*  wt    = (bf16*) (base + 56623104);     //    221,184 B -> 56,844,288
  float* segP  = (float*)(base + 56844288);     //    262,144 B -> 57,106,432
  float* segS  = (float*)(base + 57106432);     //    262,144 B -> 57,368,576
  float* segC  = (float*)(base + 57368576);     //    262,144 B -> 57,630,720
  int*   flagp = (int*)  (base + 57630720);     //  16 B -> 57,630,736
  float* zbuf  = (float*)(base + 57630736);     //  128 B zeros -> 57,630,864
  float* statb = (float*)(base + 57630864);     //  1,024 B inorm stats (mean,inv)x128
  const size_t NEED = 57631888;

  k_detect<<<dim3(1), dim3(64), 0, stream>>>(conv_w, flagp);

  if(ws_size < NEED){
    k_fill<<<dim3((out_size+255)/256), dim3(256), 0, stream>>>(d_out, out_size, flagp);
    return;
  }

  k_wprep  <<<dim3(432),   dim3(256), 0, stream>>>(conv_w, wt, zbuf, flagp);
  k_inprojm<<<dim3(512),   dim3(256), 0, stream>>>(input, inpw, xz, xin_t, flagp);
  // conv #1: xin_t -> skipb (bf16, channel-major out)
  k_convm  <<<dim3(1024),  dim3(256), 0, stream>>>(xin_t, wt, conv_b, nullptr, nullptr, skipb, nullptr, 0, flagp, zbuf);
  k_instat <<<dim3(128),   dim3(256), 0, stream>>>(skipb, statb);
  k_dirprep<<<dim3(2048),  dim3(256), 0, stream>>>(xz, c1w, c1b, xpw, bcg, dtr, flagp);
  k_scan1  <<<dim3(4096),  dim3(128), 0, stream>>>(xz, dtr, bcg, c1w, c1b, dpw, dpb, alog, ablog, psP, psS, flagp);
  k_scan2a <<<dim3(256),   dim3(256), 0, stream>>>(psP, psS, segP, segS);
  k_scan2b <<<dim3(8),     dim3(256), 0, stream>>>(segP, segS, segC);
  k_scan2c <<<dim3(256),   dim3(256), 0, stream>>>(psP, segC, psS);
  k_scan3  <<<dim3(4096),  dim3(128), 0, stream>>>(xz, dtr, bcg, c1w, c1b, dpw, dpb, alog, ablog, dskip, psS, ybuf, flagp);
  k_outln  <<<dim3(1024),  dim3(256), 0, stream>>>(ybuf, xz, opw, lng, lnb, vol_t, flagp);
  // conv #2: vol_t (+ fused inorm(skipb)) -> d_out, dual-dtype out
  k_convm  <<<dim3(1024),  dim3(256), 0, stream>>>(vol_t, wt, conv_b, skipb, statb, nullptr, d_out, 1, flagp, zbuf);
}